// Round 8
// baseline (298.111 us; speedup 1.0000x reference)
//
#include <hip/hip_runtime.h>
#include <math.h>

#define BN_EPS 1e-5f

typedef __attribute__((ext_vector_type(8))) short bf16x8;
typedef __attribute__((ext_vector_type(4))) float f32x4;

__device__ inline unsigned f2bf(float f) {
  union { float f; unsigned u; } v; v.f = f;
  unsigned r = v.u + 0x7FFF + ((v.u >> 16) & 1);   // round-nearest-even
  return r >> 16;
}

__device__ inline void acc8n(float* a, uint4 v) {
  a[0] += __uint_as_float(v.x << 16);
  a[1] += __uint_as_float(v.x & 0xffff0000u);
  a[2] += __uint_as_float(v.y << 16);
  a[3] += __uint_as_float(v.y & 0xffff0000u);
  a[4] += __uint_as_float(v.z << 16);
  a[5] += __uint_as_float(v.z & 0xffff0000u);
  a[6] += __uint_as_float(v.w << 16);
  a[7] += __uint_as_float(v.w & 0xffff0000u);
}

__device__ inline void acc4n(float* a, uint2 v) {
  a[0] += __uint_as_float(v.x << 16);
  a[1] += __uint_as_float(v.x & 0xffff0000u);
  a[2] += __uint_as_float(v.y << 16);
  a[3] += __uint_as_float(v.y & 0xffff0000u);
}

// ---------------- CSR build ----------------

__global__ void k_count(const int* __restrict__ dst, int* __restrict__ deg,
                        int* __restrict__ posw, int E) {
  int e = blockIdx.x * blockDim.x + threadIdx.x;
  if (e < E) posw[e] = atomicAdd(&deg[dst[e]], 1);
}

// single-pass scan with decoupled lookback (chunks <= 64, all blocks co-resident).
// flags[b] = chunk_total + 1 (0 = not ready), zeroed by k_prep.
__global__ void k_scan(const int* __restrict__ deg, int* __restrict__ rowstart,
                       float* __restrict__ dis, int* __restrict__ flags,
                       int n, int E) {
  __shared__ int s[1024];
  __shared__ int spre;
  const int b = blockIdx.x;
  const int tid = threadIdx.x;
  int i = b * 1024 + tid;
  int v = (i < n) ? deg[i] : 0;
  if (i < n) dis[i] = rsqrtf((float)(v + 1));   // +1 self loop
  s[tid] = v;
  __syncthreads();
  for (int off = 1; off < 1024; off <<= 1) {
    int t = (tid >= off) ? s[tid - off] : 0;
    __syncthreads();
    s[tid] += t;
    __syncthreads();
  }
  if (tid == 0) {
    spre = 0;
    atomicExch(&flags[b], s[1023] + 1);         // publish own total
  }
  __syncthreads();
  if (tid < b) {                                 // wait for predecessors (<=48)
    int v2;
    do { v2 = atomicAdd(&flags[tid], 0); } while (v2 == 0);
    atomicAdd(&spre, v2 - 1);
  }
  __syncthreads();
  int pre = spre;
  if (i < n) rowstart[i] = pre + s[tid] - v;     // global exclusive prefix
  if (b == 0 && tid == 0) rowstart[n] = E;
}

// ------ prep: deg/flags zero + BN fold (incl. bias) + weight transpose/bf16 + b3 pad ---

__global__ void k_prep(const float* __restrict__ W1, const float* __restrict__ W2,
                       const float* __restrict__ W3,
                       const float* __restrict__ g1, const float* __restrict__ be1,
                       const float* __restrict__ m1, const float* __restrict__ v1,
                       const float* __restrict__ g2, const float* __restrict__ be2,
                       const float* __restrict__ m2, const float* __restrict__ v2,
                       const float* __restrict__ b1, const float* __restrict__ b2,
                       const float* __restrict__ b3,
                       ushort* __restrict__ WT1, ushort* __restrict__ WT2,
                       ushort* __restrict__ WT3,
                       float* __restrict__ sc1, float* __restrict__ sh1,
                       float* __restrict__ sc2, float* __restrict__ sh2,
                       float* __restrict__ b3pad,
                       uint4* __restrict__ degz, int deg16,
                       uint4* __restrict__ flagz) {
  int k = blockIdx.x;      // 128
  int n = threadIdx.x;     // 128
  int tid = k * 128 + n;
  if (tid < deg16) degz[tid] = make_uint4(0, 0, 0, 0);
  if (tid < 16)    flagz[tid] = make_uint4(0, 0, 0, 0);
  WT1[n * 128 + k] = (ushort)f2bf(W1[k * 128 + n]);
  WT2[n * 128 + k] = (ushort)f2bf(W2[k * 128 + n]);
  WT3[n * 128 + k] = (n < 40) ? (ushort)f2bf(W3[k * 40 + n]) : (ushort)0;
  if (k == 0) {
    float s1 = g1[n] * rsqrtf(v1[n] + BN_EPS);
    sc1[n] = s1; sh1[n] = be1[n] + (b1[n] - m1[n]) * s1;    // bias folded in
    float s2 = g2[n] * rsqrtf(v2[n] + BN_EPS);
    sc2[n] = s2; sh2[n] = be2[n] + (b2[n] - m2[n]) * s2;
  } else if (k == 1 && n < 64) {
    b3pad[n] = (n < 40) ? b3[n] : 0.f;
  }
}

// ---- MFMA GEMM: C[r][c] = dis[r] * (A[r][:] @ W[:][c]), bf16 out.  Optional fused
// ---- CSR-fill role for blocks >= gemmBlocks (layer 1: fill hides under GEMM).

template <bool F32A, bool FILL>
__global__ __launch_bounds__(256) void k_gemm_bf16(const void* __restrict__ Ap,
                                                   const ushort* __restrict__ WT,
                                                   ushort* __restrict__ C,
                                                   const float* __restrict__ dis,
                                                   int nrows, int NC, int gemmBlocks,
                                                   const int* __restrict__ ei,
                                                   const int* __restrict__ rowstart,
                                                   const int* __restrict__ posw,
                                                   unsigned* __restrict__ slot, int E) {
  if (FILL && (int)blockIdx.x >= gemmBlocks) {
    int e = ((int)blockIdx.x - gemmBlocks) * 256 + threadIdx.x;
    if (e < E) slot[rowstart[ei[E + e]] + posw[e]] = (unsigned)ei[e];
    return;
  }
  __shared__ ushort As[128][80];
  __shared__ ushort Bs[128][80];
  const int tid  = threadIdx.x;
  const int lane = tid & 63;
  const int wid  = tid >> 6;
  const int wr   = wid >> 1, wc = wid & 1;
  const int row0 = blockIdx.x * 128;
  f32x4 acc[4][4] = {};

  const int mrow = lane & 15;
  const int kg   = (lane >> 4) * 8;

  for (int k0 = 0; k0 < 128; k0 += 64) {
    __syncthreads();
    for (int i = tid; i < 1024; i += 256) {        // A tile: 128 rows x 64 bf16
      int r = i >> 3, c = (i & 7) * 8;
      uint4 w = make_uint4(0, 0, 0, 0);
      if (row0 + r < nrows) {
        if (F32A) {
          const float* A = (const float*)Ap;
          float4 v0 = *(const float4*)(A + (size_t)(row0 + r) * 128 + k0 + c);
          float4 v1 = *(const float4*)(A + (size_t)(row0 + r) * 128 + k0 + c + 4);
          w.x = f2bf(v0.x) | (f2bf(v0.y) << 16);
          w.y = f2bf(v0.z) | (f2bf(v0.w) << 16);
          w.z = f2bf(v1.x) | (f2bf(v1.y) << 16);
          w.w = f2bf(v1.z) | (f2bf(v1.w) << 16);
        } else {
          const ushort* A = (const ushort*)Ap;
          w = *(const uint4*)(A + (size_t)(row0 + r) * 128 + k0 + c);
        }
      }
      *(uint4*)(&As[r][c]) = w;
    }
    for (int i = tid; i < 1024; i += 256) {        // B tile: 128 n-rows x 64 bf16 (k)
      int r = i >> 3, c = (i & 7) * 8;
      *(uint4*)(&Bs[r][c]) = *(const uint4*)(WT + r * 128 + k0 + c);
    }
    __syncthreads();

#pragma unroll
    for (int ks = 0; ks < 2; ks++) {
      bf16x8 a[4], b[4];
#pragma unroll
      for (int f = 0; f < 4; f++) {
        a[f] = *(const bf16x8*)(&As[wr * 64 + f * 16 + mrow][ks * 32 + kg]);
        b[f] = *(const bf16x8*)(&Bs[wc * 64 + f * 16 + mrow][ks * 32 + kg]);
      }
#pragma unroll
      for (int fm = 0; fm < 4; fm++)
#pragma unroll
        for (int fn = 0; fn < 4; fn++)
          acc[fm][fn] = __builtin_amdgcn_mfma_f32_16x16x32_bf16(a[fm], b[fn], acc[fm][fn], 0, 0, 0);
    }
  }

  // C/D layout: col = lane&15, row = (lane>>4)*4 + reg
  const int rl = (lane >> 4) * 4;
  const int cl = lane & 15;
#pragma unroll
  for (int fm = 0; fm < 4; fm++) {
#pragma unroll
    for (int r = 0; r < 4; r++) {
      int row = row0 + wr * 64 + fm * 16 + rl + r;
      if (row >= nrows) continue;
      float dn = dis[row];
#pragma unroll
      for (int fn = 0; fn < 4; fn++) {
        int col = wc * 64 + fn * 16 + cl;
        if (col < NC) C[(size_t)row * NC + col] = (ushort)f2bf(acc[fm][fn][r] * dn);
      }
    }
  }
}

// ---- XCD-chunked aggregation (D=128, 4 chunks x 32 ch, 16B/lane loads) ----------------
// chunk = wgid & 3: with round-robin wg->XCD (wgid%8), chunk c lands on XCDs {c, c+4};
// per-XCD h-slice = 3.2 MB -> L2-resident. Wave = 16 edge-groups x 4 lanes x 16B.

__global__ __launch_bounds__(256) void k_agg128x(const ushort* __restrict__ h,
                          const int* __restrict__ rowstart,
                          const unsigned* __restrict__ slot,
                          const float* __restrict__ dis,
                          const float* __restrict__ bnsc,
                          const float* __restrict__ bnsh,
                          ushort* __restrict__ out, int nnodes) {
  int wgid  = blockIdx.x;
  int chunk = wgid & 3;
  int node  = (wgid >> 2) * 4 + threadIdx.y;
  if (node >= nnodes) return;
  int lane = threadIdx.x;
  int g  = lane >> 2;                       // edge group 0..15
  int c0 = chunk * 32 + (lane & 3) * 8;     // 8 channels (16B)
  int s = rowstart[node], e = rowstart[node + 1];
  int deg = e - s;
  unsigned mys = 0;
  if (lane < deg) mys = slot[s + lane];
  float a[8] = {0.f, 0.f, 0.f, 0.f, 0.f, 0.f, 0.f, 0.f};
  int nb = deg < 64 ? deg : 64;
  for (int i = g; i < nb; i += 16) {        // 16 edges in flight per wave
    int s0 = __shfl((int)mys, i);
    uint4 hv = *(const uint4*)(h + (size_t)s0 * 128 + c0);
    acc8n(a, hv);
  }
  for (int j = s + 64 + g; j < e; j += 16) { // rare tail (deg > 64)
    uint4 hv = *(const uint4*)(h + (size_t)slot[j] * 128 + c0);
    acc8n(a, hv);
  }
#pragma unroll
  for (int j = 0; j < 8; j++) {              // reduce over the 16 groups (bits 2..5)
    a[j] += __shfl_xor(a[j], 4);
    a[j] += __shfl_xor(a[j], 8);
    a[j] += __shfl_xor(a[j], 16);
    a[j] += __shfl_xor(a[j], 32);
  }
  if (g == 0) {                              // lanes 0..3 write the chunk slice
    uint4 hv = *(const uint4*)(h + (size_t)node * 128 + c0);
    acc8n(a, hv);                            // self loop
    float dn = dis[node];
    float4 sc0 = *(const float4*)(bnsc + c0), sc1 = *(const float4*)(bnsc + c0 + 4);
    float4 sh0 = *(const float4*)(bnsh + c0), sh1 = *(const float4*)(bnsh + c0 + 4);
    float o0 = fmaxf(fmaf(a[0] * dn, sc0.x, sh0.x), 0.f);
    float o1 = fmaxf(fmaf(a[1] * dn, sc0.y, sh0.y), 0.f);
    float o2 = fmaxf(fmaf(a[2] * dn, sc0.z, sh0.z), 0.f);
    float o3 = fmaxf(fmaf(a[3] * dn, sc0.w, sh0.w), 0.f);
    float o4 = fmaxf(fmaf(a[4] * dn, sc1.x, sh1.x), 0.f);
    float o5 = fmaxf(fmaf(a[5] * dn, sc1.y, sh1.y), 0.f);
    float o6 = fmaxf(fmaf(a[6] * dn, sc1.z, sh1.z), 0.f);
    float o7 = fmaxf(fmaf(a[7] * dn, sc1.w, sh1.w), 0.f);
    uint4 w;
    w.x = f2bf(o0) | (f2bf(o1) << 16);
    w.y = f2bf(o2) | (f2bf(o3) << 16);
    w.z = f2bf(o4) | (f2bf(o5) << 16);
    w.w = f2bf(o6) | (f2bf(o7) << 16);
    *(uint4*)(out + (size_t)node * 128 + c0) = w;
  }
}

// -------- Aggregation (40-ch layer-3 rows, 4.0 MB = L2-resident) + log_softmax ---------

__global__ __launch_bounds__(256) void k_agg40_lsm(const ushort* __restrict__ h,
                            const int* __restrict__ rowstart,
                            const unsigned* __restrict__ slot,
                            const float* __restrict__ dis,
                            const float* __restrict__ b3pad,
                            float* __restrict__ out, int nnodes) {
  int node = blockIdx.x * 4 + threadIdx.y;
  if (node >= nnodes) return;
  int lane = threadIdx.x;
  int eg = lane >> 4, cl = lane & 15, c0 = cl * 4;
  bool act = cl < 10;                            // channels 4*cl..4*cl+3 < 40
  int s = rowstart[node], e = rowstart[node + 1];
  int deg = e - s;
  unsigned mys = 0;
  if (lane < deg) mys = slot[s + lane];
  float a[4] = {0.f, 0.f, 0.f, 0.f};
  int nb = deg < 64 ? deg : 64;
  int i = eg;
  for (; i + 12 < nb; i += 16) {
    int s0 = __shfl((int)mys, i);
    int s1 = __shfl((int)mys, i + 4);
    int s2 = __shfl((int)mys, i + 8);
    int s3 = __shfl((int)mys, i + 12);
    if (act) {
      uint2 h0 = *(const uint2*)(h + (size_t)s0 * 40 + c0);
      uint2 h1 = *(const uint2*)(h + (size_t)s1 * 40 + c0);
      uint2 h2 = *(const uint2*)(h + (size_t)s2 * 40 + c0);
      uint2 h3 = *(const uint2*)(h + (size_t)s3 * 40 + c0);
      acc4n(a, h0); acc4n(a, h1); acc4n(a, h2); acc4n(a, h3);
    }
  }
  for (; i + 4 < nb; i += 8) {
    int s0 = __shfl((int)mys, i);
    int s1 = __shfl((int)mys, i + 4);
    if (act) {
      uint2 h0 = *(const uint2*)(h + (size_t)s0 * 40 + c0);
      uint2 h1 = *(const uint2*)(h + (size_t)s1 * 40 + c0);
      acc4n(a, h0); acc4n(a, h1);
    }
  }
  if (i < nb) {
    int s0 = __shfl((int)mys, i);
    if (act) acc4n(a, *(const uint2*)(h + (size_t)s0 * 40 + c0));
  }
  for (int j = s + 64 + eg; j < e; j += 4) {
    unsigned sj = slot[j];
    if (act) acc4n(a, *(const uint2*)(h + (size_t)sj * 40 + c0));
  }
#pragma unroll
  for (int j = 0; j < 4; j++) {
    a[j] += __shfl_xor(a[j], 16);
    a[j] += __shfl_xor(a[j], 32);
  }
  // self loop + dis scale + bias (identical across edge groups)
  if (act) {
    acc4n(a, *(const uint2*)(h + (size_t)node * 40 + c0));
    float dn = dis[node];
    float4 bb = *(const float4*)(b3pad + c0);
    a[0] = fmaf(a[0], dn, bb.x);
    a[1] = fmaf(a[1], dn, bb.y);
    a[2] = fmaf(a[2], dn, bb.z);
    a[3] = fmaf(a[3], dn, bb.w);
  }
  float m = act ? fmaxf(fmaxf(a[0], a[1]), fmaxf(a[2], a[3])) : -INFINITY;
#pragma unroll
  for (int off = 1; off < 16; off <<= 1) m = fmaxf(m, __shfl_xor(m, off));
  float ss = act ? (expf(a[0] - m) + expf(a[1] - m) + expf(a[2] - m) + expf(a[3] - m)) : 0.f;
#pragma unroll
  for (int off = 1; off < 16; off <<= 1) ss += __shfl_xor(ss, off);
  float lse = m + logf(ss);
  if (eg == 0 && act) {
    *(float4*)(out + (size_t)node * 40 + c0) =
        make_float4(a[0] - lse, a[1] - lse, a[2] - lse, a[3] - lse);
  }
}

// ---------------- launch ----------------

extern "C" void kernel_launch(void* const* d_in, const int* in_sizes, int n_in,
                              void* d_out, int out_size, void* d_ws, size_t ws_size,
                              hipStream_t stream) {
  const float* x   = (const float*)d_in[0];
  const int*   ei  = (const int*)d_in[1];
  const float* W1  = (const float*)d_in[2];
  const float* b1  = (const float*)d_in[3];
  const float* W2  = (const float*)d_in[4];
  const float* b2  = (const float*)d_in[5];
  const float* W3  = (const float*)d_in[6];
  const float* b3  = (const float*)d_in[7];
  const float* g1  = (const float*)d_in[8];
  const float* be1 = (const float*)d_in[9];
  const float* m1  = (const float*)d_in[10];
  const float* v1  = (const float*)d_in[11];
  const float* g2  = (const float*)d_in[12];
  const float* be2 = (const float*)d_in[13];
  const float* m2  = (const float*)d_in[14];
  const float* v2  = (const float*)d_in[15];

  const int N   = in_sizes[0] / 128;
  const int E   = in_sizes[1] / 2;

  float* outp = (float*)d_out;

  char* ws = (char*)d_ws;
  size_t off = 0;
  auto alloc = [&](size_t bytes) -> char* {
    char* p = ws + off;
    off = (off + bytes + 255) & ~(size_t)255;
    return p;
  };
  const int deg16 = (N + 3) / 4;
  int*      deg      = (int*)alloc((size_t)deg16 * 16);
  int*      flags    = (int*)alloc(64 * 4);
  int*      posw     = (int*)alloc((size_t)E * 4);
  int*      rowstart = (int*)alloc((size_t)(N + 1) * 4);
  float*    dis      = (float*)alloc((size_t)N * 4);
  unsigned* slot     = (unsigned*)alloc((size_t)E * 4);
  float*    sc1      = (float*)alloc(128 * 4);
  float*    sh1      = (float*)alloc(128 * 4);
  float*    sc2      = (float*)alloc(128 * 4);
  float*    sh2      = (float*)alloc(128 * 4);
  float*    b3pad    = (float*)alloc(64 * 4);
  ushort*   WT1      = (ushort*)alloc(128 * 128 * 2);
  ushort*   WT2      = (ushort*)alloc(128 * 128 * 2);
  ushort*   WT3      = (ushort*)alloc(128 * 128 * 2);
  ushort*   bufA     = (ushort*)alloc((size_t)N * 128 * 2);
  ushort*   bufB     = (ushort*)alloc((size_t)N * 128 * 2);
  ushort*   bufC     = (ushort*)alloc((size_t)N * 40 * 2);
  (void)ws_size;

  const int T = 256;
  const int chunks = (N + 1023) / 1024;   // 49 <= 64

  // prep (zeroes deg+flags) -> count -> single-pass scan
  k_prep<<<128, 128, 0, stream>>>(W1, W2, W3, g1, be1, m1, v1, g2, be2, m2, v2,
                                  b1, b2, b3, WT1, WT2, WT3, sc1, sh1, sc2, sh2, b3pad,
                                  (uint4*)deg, deg16, (uint4*)flags);
  k_count<<<(E + T - 1) / T, T, 0, stream>>>(ei + E, deg, posw, E);
  k_scan<<<chunks, 1024, 0, stream>>>(deg, rowstart, dis, flags, N, E);

  const int quads = (N + 3) / 4;
  dim3 aggBlk(64, 4);
  const int gBlocks = (N + 127) / 128;
  const int fBlocks = (E + 255) / 256;

  // Layer 1: GEMM (fp32 in, dis-scaled bf16 out) with CSR fill fused in extra blocks
  k_gemm_bf16<true, true><<<gBlocks + fBlocks, 256, 0, stream>>>(
      x, WT1, bufB, dis, N, 128, gBlocks, ei, rowstart, posw, slot, E);
  k_agg128x<<<4 * quads, aggBlk, 0, stream>>>(bufB, rowstart, slot, dis, sc1, sh1, bufA, N);

  // Layer 2
  k_gemm_bf16<false, false><<<gBlocks, 256, 0, stream>>>(
      bufA, WT2, bufB, dis, N, 128, gBlocks, nullptr, nullptr, nullptr, nullptr, 0);
  k_agg128x<<<4 * quads, aggBlk, 0, stream>>>(bufB, rowstart, slot, dis, sc2, sh2, bufA, N);

  // Layer 3 (40-ch rows) + log_softmax
  k_gemm_bf16<false, false><<<gBlocks, 256, 0, stream>>>(
      bufA, WT3, bufC, dis, N, 40, gBlocks, nullptr, nullptr, nullptr, nullptr, 0);
  k_agg40_lsm<<<quads, aggBlk, 0, stream>>>(bufC, rowstart, slot, dis, b3pad, outp, N);
}

// Round 9
// 201.624 us; speedup vs baseline: 1.4785x; 1.4785x over previous
//
#include <hip/hip_runtime.h>
#include <math.h>

#define BN_EPS 1e-5f

typedef __attribute__((ext_vector_type(8))) short bf16x8;
typedef __attribute__((ext_vector_type(4))) float f32x4;

__device__ inline unsigned f2bf(float f) {
  union { float f; unsigned u; } v; v.f = f;
  unsigned r = v.u + 0x7FFF + ((v.u >> 16) & 1);   // round-nearest-even
  return r >> 16;
}

__device__ inline void acc8n(float* a, uint4 v) {
  a[0] += __uint_as_float(v.x << 16);
  a[1] += __uint_as_float(v.x & 0xffff0000u);
  a[2] += __uint_as_float(v.y << 16);
  a[3] += __uint_as_float(v.y & 0xffff0000u);
  a[4] += __uint_as_float(v.z << 16);
  a[5] += __uint_as_float(v.z & 0xffff0000u);
  a[6] += __uint_as_float(v.w << 16);
  a[7] += __uint_as_float(v.w & 0xffff0000u);
}

__device__ inline void acc4n(float* a, uint2 v) {
  a[0] += __uint_as_float(v.x << 16);
  a[1] += __uint_as_float(v.x & 0xffff0000u);
  a[2] += __uint_as_float(v.y << 16);
  a[3] += __uint_as_float(v.y & 0xffff0000u);
}

// ---------------- zero (deg + flags) ----------------

__global__ void k_zero(uint4* __restrict__ deg, int n16, uint4* __restrict__ flags) {
  int i = blockIdx.x * blockDim.x + threadIdx.x;
  if (i < n16) deg[i] = make_uint4(0, 0, 0, 0);
  if (i < 16) flags[i] = make_uint4(0, 0, 0, 0);
}

// ------ fused count + prep: blocks 0..63 do weight transpose/BN fold (hides under
// ------ the 800k-atomic degree count in blocks 64+) ------------------------------------

__global__ __launch_bounds__(256) void k_count_prep(
    const int* __restrict__ ei, int E, int* __restrict__ deg, int* __restrict__ posw,
    const float* __restrict__ W1, const float* __restrict__ W2,
    const float* __restrict__ W3,
    const float* __restrict__ g1, const float* __restrict__ be1,
    const float* __restrict__ m1, const float* __restrict__ v1,
    const float* __restrict__ g2, const float* __restrict__ be2,
    const float* __restrict__ m2, const float* __restrict__ v2,
    const float* __restrict__ b1, const float* __restrict__ b2,
    const float* __restrict__ b3,
    ushort* __restrict__ WT1, ushort* __restrict__ WT2, ushort* __restrict__ WT3,
    float* __restrict__ sc1, float* __restrict__ sh1,
    float* __restrict__ sc2, float* __restrict__ sh2,
    float* __restrict__ b3pad) {
  int b = blockIdx.x;
  int tid = threadIdx.x;
  if (b < 64) {                     // prep role: 64 blocks x 2 W-rows each
    int k = b * 2 + (tid >> 7);
    int n = tid & 127;
    WT1[n * 128 + k] = (ushort)f2bf(W1[k * 128 + n]);
    WT2[n * 128 + k] = (ushort)f2bf(W2[k * 128 + n]);
    WT3[n * 128 + k] = (n < 40) ? (ushort)f2bf(W3[k * 40 + n]) : (ushort)0;
    if (k == 0) {
      float s1 = g1[n] * rsqrtf(v1[n] + BN_EPS);
      sc1[n] = s1; sh1[n] = be1[n] + (b1[n] - m1[n]) * s1;    // bias folded in
      float s2 = g2[n] * rsqrtf(v2[n] + BN_EPS);
      sc2[n] = s2; sh2[n] = be2[n] + (b2[n] - m2[n]) * s2;
    } else if (k == 1 && n < 64) {
      b3pad[n] = (n < 40) ? b3[n] : 0.f;
    }
    return;
  }
  int e = (b - 64) * 256 + tid;     // count role
  if (e < E) posw[e] = atomicAdd(&deg[ei[E + e]], 1);
}

// single-pass scan with decoupled lookback (chunks <= 64, all blocks co-resident).
__global__ void k_scan(const int* __restrict__ deg, int* __restrict__ rowstart,
                       float* __restrict__ dis, int* __restrict__ flags,
                       int n, int E) {
  __shared__ int s[1024];
  __shared__ int spre;
  const int b = blockIdx.x;
  const int tid = threadIdx.x;
  int i = b * 1024 + tid;
  int v = (i < n) ? deg[i] : 0;
  if (i < n) dis[i] = rsqrtf((float)(v + 1));   // +1 self loop
  s[tid] = v;
  __syncthreads();
  for (int off = 1; off < 1024; off <<= 1) {
    int t = (tid >= off) ? s[tid - off] : 0;
    __syncthreads();
    s[tid] += t;
    __syncthreads();
  }
  if (tid == 0) {
    spre = 0;
    atomicExch(&flags[b], s[1023] + 1);         // publish own total
  }
  __syncthreads();
  if (tid < b) {                                 // wait for predecessors (<=48)
    int v2;
    do { v2 = atomicAdd(&flags[tid], 0); } while (v2 == 0);
    atomicAdd(&spre, v2 - 1);
  }
  __syncthreads();
  int pre = spre;
  if (i < n) rowstart[i] = pre + s[tid] - v;     // global exclusive prefix
  if (b == 0 && tid == 0) rowstart[n] = E;
}

// ---- MFMA GEMM: C[r][c] = dis[r] * (A[r][:] @ W[:][c]), bf16 out.  Optional fused
// ---- CSR-fill role for blocks >= gemmBlocks (layer 1: fill hides under GEMM).

template <bool F32A, bool FILL>
__global__ __launch_bounds__(256) void k_gemm_bf16(const void* __restrict__ Ap,
                                                   const ushort* __restrict__ WT,
                                                   ushort* __restrict__ C,
                                                   const float* __restrict__ dis,
                                                   int nrows, int NC, int gemmBlocks,
                                                   const int* __restrict__ ei,
                                                   const int* __restrict__ rowstart,
                                                   const int* __restrict__ posw,
                                                   unsigned* __restrict__ slot, int E) {
  if (FILL && (int)blockIdx.x >= gemmBlocks) {
    int e = ((int)blockIdx.x - gemmBlocks) * 256 + threadIdx.x;
    if (e < E) slot[rowstart[ei[E + e]] + posw[e]] = (unsigned)ei[e];
    return;
  }
  __shared__ ushort As[128][80];
  __shared__ ushort Bs[128][80];
  const int tid  = threadIdx.x;
  const int lane = tid & 63;
  const int wid  = tid >> 6;
  const int wr   = wid >> 1, wc = wid & 1;
  const int row0 = blockIdx.x * 128;
  f32x4 acc[4][4] = {};

  const int mrow = lane & 15;
  const int kg   = (lane >> 4) * 8;

  for (int k0 = 0; k0 < 128; k0 += 64) {
    __syncthreads();
    for (int i = tid; i < 1024; i += 256) {        // A tile: 128 rows x 64 bf16
      int r = i >> 3, c = (i & 7) * 8;
      uint4 w = make_uint4(0, 0, 0, 0);
      if (row0 + r < nrows) {
        if (F32A) {
          const float* A = (const float*)Ap;
          float4 v0 = *(const float4*)(A + (size_t)(row0 + r) * 128 + k0 + c);
          float4 v1 = *(const float4*)(A + (size_t)(row0 + r) * 128 + k0 + c + 4);
          w.x = f2bf(v0.x) | (f2bf(v0.y) << 16);
          w.y = f2bf(v0.z) | (f2bf(v0.w) << 16);
          w.z = f2bf(v1.x) | (f2bf(v1.y) << 16);
          w.w = f2bf(v1.z) | (f2bf(v1.w) << 16);
        } else {
          const ushort* A = (const ushort*)Ap;
          w = *(const uint4*)(A + (size_t)(row0 + r) * 128 + k0 + c);
        }
      }
      *(uint4*)(&As[r][c]) = w;
    }
    for (int i = tid; i < 1024; i += 256) {        // B tile: 128 n-rows x 64 bf16 (k)
      int r = i >> 3, c = (i & 7) * 8;
      *(uint4*)(&Bs[r][c]) = *(const uint4*)(WT + r * 128 + k0 + c);
    }
    __syncthreads();

#pragma unroll
    for (int ks = 0; ks < 2; ks++) {
      bf16x8 a[4], b[4];
#pragma unroll
      for (int f = 0; f < 4; f++) {
        a[f] = *(const bf16x8*)(&As[wr * 64 + f * 16 + mrow][ks * 32 + kg]);
        b[f] = *(const bf16x8*)(&Bs[wc * 64 + f * 16 + mrow][ks * 32 + kg]);
      }
#pragma unroll
      for (int fm = 0; fm < 4; fm++)
#pragma unroll
        for (int fn = 0; fn < 4; fn++)
          acc[fm][fn] = __builtin_amdgcn_mfma_f32_16x16x32_bf16(a[fm], b[fn], acc[fm][fn], 0, 0, 0);
    }
  }

  // C/D layout: col = lane&15, row = (lane>>4)*4 + reg
  const int rl = (lane >> 4) * 4;
  const int cl = lane & 15;
#pragma unroll
  for (int fm = 0; fm < 4; fm++) {
#pragma unroll
    for (int r = 0; r < 4; r++) {
      int row = row0 + wr * 64 + fm * 16 + rl + r;
      if (row >= nrows) continue;
      float dn = dis[row];
#pragma unroll
      for (int fn = 0; fn < 4; fn++) {
        int col = wc * 64 + fn * 16 + cl;
        if (col < NC) C[(size_t)row * NC + col] = (ushort)f2bf(acc[fm][fn][r] * dn);
      }
    }
  }
}

// ---- Aggregation (D=128): out = relu(sc*(dis[n]*(Σ h'[src] + h'[n])) + sh), bf16 ------
// r6-proven shape: wave = 4 edge-groups x 16 lanes; lane gathers 8 ch (16B); 4-deep ILP.

__global__ __launch_bounds__(256) void k_agg128b(const ushort* __restrict__ h,
                          const int* __restrict__ rowstart,
                          const unsigned* __restrict__ slot,
                          const float* __restrict__ dis,
                          const float* __restrict__ bnsc,
                          const float* __restrict__ bnsh,
                          ushort* __restrict__ out, int nnodes) {
  int node = blockIdx.x * 4 + threadIdx.y;
  if (node >= nnodes) return;
  int lane = threadIdx.x;
  int eg = lane >> 4, cl = lane & 15, c0 = cl * 8;
  int s = rowstart[node], e = rowstart[node + 1];
  int deg = e - s;
  unsigned mys = 0;
  if (lane < deg) mys = slot[s + lane];
  float a[8] = {0.f, 0.f, 0.f, 0.f, 0.f, 0.f, 0.f, 0.f};
  int nb = deg < 64 ? deg : 64;
  int i = eg;
  for (; i + 12 < nb; i += 16) {                 // 4 independent gathers in flight
    int s0 = __shfl((int)mys, i);
    int s1 = __shfl((int)mys, i + 4);
    int s2 = __shfl((int)mys, i + 8);
    int s3 = __shfl((int)mys, i + 12);
    uint4 h0 = *(const uint4*)(h + (size_t)s0 * 128 + c0);
    uint4 h1 = *(const uint4*)(h + (size_t)s1 * 128 + c0);
    uint4 h2 = *(const uint4*)(h + (size_t)s2 * 128 + c0);
    uint4 h3 = *(const uint4*)(h + (size_t)s3 * 128 + c0);
    acc8n(a, h0); acc8n(a, h1); acc8n(a, h2); acc8n(a, h3);
  }
  for (; i + 4 < nb; i += 8) {
    int s0 = __shfl((int)mys, i);
    int s1 = __shfl((int)mys, i + 4);
    uint4 h0 = *(const uint4*)(h + (size_t)s0 * 128 + c0);
    uint4 h1 = *(const uint4*)(h + (size_t)s1 * 128 + c0);
    acc8n(a, h0); acc8n(a, h1);
  }
  if (i < nb) {
    int s0 = __shfl((int)mys, i);
    uint4 h0 = *(const uint4*)(h + (size_t)s0 * 128 + c0);
    acc8n(a, h0);
  }
  for (int j = s + 64 + eg; j < e; j += 4) {     // rare tail (deg > 64)
    uint4 h0 = *(const uint4*)(h + (size_t)slot[j] * 128 + c0);
    acc8n(a, h0);
  }
#pragma unroll
  for (int j = 0; j < 8; j++) {
    a[j] += __shfl_xor(a[j], 16);
    a[j] += __shfl_xor(a[j], 32);
  }
  if (eg == 0) {
    uint4 hv = *(const uint4*)(h + (size_t)node * 128 + c0);
    acc8n(a, hv);                                 // self loop
    float dn = dis[node];
    float4 sc0 = *(const float4*)(bnsc + c0), sc1 = *(const float4*)(bnsc + c0 + 4);
    float4 sh0 = *(const float4*)(bnsh + c0), sh1 = *(const float4*)(bnsh + c0 + 4);
    float o0 = fmaxf(fmaf(a[0] * dn, sc0.x, sh0.x), 0.f);
    float o1 = fmaxf(fmaf(a[1] * dn, sc0.y, sh0.y), 0.f);
    float o2 = fmaxf(fmaf(a[2] * dn, sc0.z, sh0.z), 0.f);
    float o3 = fmaxf(fmaf(a[3] * dn, sc0.w, sh0.w), 0.f);
    float o4 = fmaxf(fmaf(a[4] * dn, sc1.x, sh1.x), 0.f);
    float o5 = fmaxf(fmaf(a[5] * dn, sc1.y, sh1.y), 0.f);
    float o6 = fmaxf(fmaf(a[6] * dn, sc1.z, sh1.z), 0.f);
    float o7 = fmaxf(fmaf(a[7] * dn, sc1.w, sh1.w), 0.f);
    uint4 w;
    w.x = f2bf(o0) | (f2bf(o1) << 16);
    w.y = f2bf(o2) | (f2bf(o3) << 16);
    w.z = f2bf(o4) | (f2bf(o5) << 16);
    w.w = f2bf(o6) | (f2bf(o7) << 16);
    *(uint4*)(out + (size_t)node * 128 + c0) = w;
  }
}

// -------- Aggregation (40-ch layer-3 rows) + log_softmax (fp32 out, 40 ch) -------------

__global__ __launch_bounds__(256) void k_agg40_lsm(const ushort* __restrict__ h,
                            const int* __restrict__ rowstart,
                            const unsigned* __restrict__ slot,
                            const float* __restrict__ dis,
                            const float* __restrict__ b3pad,
                            float* __restrict__ out, int nnodes) {
  int node = blockIdx.x * 4 + threadIdx.y;
  if (node >= nnodes) return;
  int lane = threadIdx.x;
  int eg = lane >> 4, cl = lane & 15, c0 = cl * 4;
  bool act = cl < 10;                            // channels 4*cl..4*cl+3 < 40
  int s = rowstart[node], e = rowstart[node + 1];
  int deg = e - s;
  unsigned mys = 0;
  if (lane < deg) mys = slot[s + lane];
  float a[4] = {0.f, 0.f, 0.f, 0.f};
  int nb = deg < 64 ? deg : 64;
  int i = eg;
  for (; i + 12 < nb; i += 16) {
    int s0 = __shfl((int)mys, i);
    int s1 = __shfl((int)mys, i + 4);
    int s2 = __shfl((int)mys, i + 8);
    int s3 = __shfl((int)mys, i + 12);
    if (act) {
      uint2 h0 = *(const uint2*)(h + (size_t)s0 * 40 + c0);
      uint2 h1 = *(const uint2*)(h + (size_t)s1 * 40 + c0);
      uint2 h2 = *(const uint2*)(h + (size_t)s2 * 40 + c0);
      uint2 h3 = *(const uint2*)(h + (size_t)s3 * 40 + c0);
      acc4n(a, h0); acc4n(a, h1); acc4n(a, h2); acc4n(a, h3);
    }
  }
  for (; i + 4 < nb; i += 8) {
    int s0 = __shfl((int)mys, i);
    int s1 = __shfl((int)mys, i + 4);
    if (act) {
      uint2 h0 = *(const uint2*)(h + (size_t)s0 * 40 + c0);
      uint2 h1 = *(const uint2*)(h + (size_t)s1 * 40 + c0);
      acc4n(a, h0); acc4n(a, h1);
    }
  }
  if (i < nb) {
    int s0 = __shfl((int)mys, i);
    if (act) acc4n(a, *(const uint2*)(h + (size_t)s0 * 40 + c0));
  }
  for (int j = s + 64 + eg; j < e; j += 4) {
    unsigned sj = slot[j];
    if (act) acc4n(a, *(const uint2*)(h + (size_t)sj * 40 + c0));
  }
#pragma unroll
  for (int j = 0; j < 4; j++) {
    a[j] += __shfl_xor(a[j], 16);
    a[j] += __shfl_xor(a[j], 32);
  }
  // self loop + dis scale + bias (identical across edge groups)
  if (act) {
    acc4n(a, *(const uint2*)(h + (size_t)node * 40 + c0));
    float dn = dis[node];
    float4 bb = *(const float4*)(b3pad + c0);
    a[0] = fmaf(a[0], dn, bb.x);
    a[1] = fmaf(a[1], dn, bb.y);
    a[2] = fmaf(a[2], dn, bb.z);
    a[3] = fmaf(a[3], dn, bb.w);
  }
  float m = act ? fmaxf(fmaxf(a[0], a[1]), fmaxf(a[2], a[3])) : -INFINITY;
#pragma unroll
  for (int off = 1; off < 16; off <<= 1) m = fmaxf(m, __shfl_xor(m, off));
  float ss = act ? (expf(a[0] - m) + expf(a[1] - m) + expf(a[2] - m) + expf(a[3] - m)) : 0.f;
#pragma unroll
  for (int off = 1; off < 16; off <<= 1) ss += __shfl_xor(ss, off);
  float lse = m + logf(ss);
  if (eg == 0 && act) {
    *(float4*)(out + (size_t)node * 40 + c0) =
        make_float4(a[0] - lse, a[1] - lse, a[2] - lse, a[3] - lse);
  }
}

// ---------------- launch ----------------

extern "C" void kernel_launch(void* const* d_in, const int* in_sizes, int n_in,
                              void* d_out, int out_size, void* d_ws, size_t ws_size,
                              hipStream_t stream) {
  const float* x   = (const float*)d_in[0];
  const int*   ei  = (const int*)d_in[1];
  const float* W1  = (const float*)d_in[2];
  const float* b1  = (const float*)d_in[3];
  const float* W2  = (const float*)d_in[4];
  const float* b2  = (const float*)d_in[5];
  const float* W3  = (const float*)d_in[6];
  const float* b3  = (const float*)d_in[7];
  const float* g1  = (const float*)d_in[8];
  const float* be1 = (const float*)d_in[9];
  const float* m1  = (const float*)d_in[10];
  const float* v1  = (const float*)d_in[11];
  const float* g2  = (const float*)d_in[12];
  const float* be2 = (const float*)d_in[13];
  const float* m2  = (const float*)d_in[14];
  const float* v2  = (const float*)d_in[15];

  const int N   = in_sizes[0] / 128;
  const int E   = in_sizes[1] / 2;

  float* outp = (float*)d_out;

  char* ws = (char*)d_ws;
  size_t off = 0;
  auto alloc = [&](size_t bytes) -> char* {
    char* p = ws + off;
    off = (off + bytes + 255) & ~(size_t)255;
    return p;
  };
  const int deg16 = (N + 3) / 4;
  int*      deg      = (int*)alloc((size_t)deg16 * 16);
  int*      flags    = (int*)alloc(64 * 4);
  int*      posw     = (int*)alloc((size_t)E * 4);
  int*      rowstart = (int*)alloc((size_t)(N + 1) * 4);
  float*    dis      = (float*)alloc((size_t)N * 4);
  unsigned* slot     = (unsigned*)alloc((size_t)E * 4);
  float*    sc1      = (float*)alloc(128 * 4);
  float*    sh1      = (float*)alloc(128 * 4);
  float*    sc2      = (float*)alloc(128 * 4);
  float*    sh2      = (float*)alloc(128 * 4);
  float*    b3pad    = (float*)alloc(64 * 4);
  ushort*   WT1      = (ushort*)alloc(128 * 128 * 2);
  ushort*   WT2      = (ushort*)alloc(128 * 128 * 2);
  ushort*   WT3      = (ushort*)alloc(128 * 128 * 2);
  ushort*   bufA     = (ushort*)alloc((size_t)N * 128 * 2);
  ushort*   bufB     = (ushort*)alloc((size_t)N * 128 * 2);
  ushort*   bufC     = (ushort*)alloc((size_t)N * 40 * 2);
  (void)ws_size;

  const int T = 256;
  const int chunks = (N + 1023) / 1024;   // 49 <= 64
  const int cBlocks = (E + 255) / 256;

  // zero -> fused count+prep -> single-pass scan
  k_zero<<<(deg16 + T - 1) / T, T, 0, stream>>>((uint4*)deg, deg16, (uint4*)flags);
  k_count_prep<<<64 + cBlocks, 256, 0, stream>>>(
      ei, E, deg, posw, W1, W2, W3, g1, be1, m1, v1, g2, be2, m2, v2,
      b1, b2, b3, WT1, WT2, WT3, sc1, sh1, sc2, sh2, b3pad);
  k_scan<<<chunks, 1024, 0, stream>>>(deg, rowstart, dis, flags, N, E);

  const int quads = (N + 3) / 4;
  dim3 aggBlk(64, 4);
  const int gBlocks = (N + 127) / 128;

  // Layer 1: GEMM (fp32 in, dis-scaled bf16 out) with CSR fill fused in extra blocks
  k_gemm_bf16<true, true><<<gBlocks + cBlocks, 256, 0, stream>>>(
      x, WT1, bufB, dis, N, 128, gBlocks, ei, rowstart, posw, slot, E);
  k_agg128b<<<quads, aggBlk, 0, stream>>>(bufB, rowstart, slot, dis, sc1, sh1, bufA, N);

  // Layer 2
  k_gemm_bf16<false, false><<<gBlocks, 256, 0, stream>>>(
      bufA, WT2, bufB, dis, N, 128, gBlocks, nullptr, nullptr, nullptr, nullptr, 0);
  k_agg128b<<<quads, aggBlk, 0, stream>>>(bufB, rowstart, slot, dis, sc2, sh2, bufA, N);

  // Layer 3 (40-ch rows) + log_softmax
  k_gemm_bf16<false, false><<<gBlocks, 256, 0, stream>>>(
      bufA, WT3, bufC, dis, N, 40, gBlocks, nullptr, nullptr, nullptr, nullptr, 0);
  k_agg40_lsm<<<quads, aggBlk, 0, stream>>>(bufC, rowstart, slot, dis, b3pad, outp, N);
}

// Round 10
// 184.434 us; speedup vs baseline: 1.6164x; 1.0932x over previous
//
#include <hip/hip_runtime.h>
#include <math.h>

#define BN_EPS 1e-5f

typedef __attribute__((ext_vector_type(8))) short bf16x8;
typedef __attribute__((ext_vector_type(4))) float f32x4;

__device__ inline unsigned f2bf(float f) {
  union { float f; unsigned u; } v; v.f = f;
  unsigned r = v.u + 0x7FFF + ((v.u >> 16) & 1);   // round-nearest-even
  return r >> 16;
}

__device__ inline void acc8n(float* a, uint4 v) {
  a[0] += __uint_as_float(v.x << 16);
  a[1] += __uint_as_float(v.x & 0xffff0000u);
  a[2] += __uint_as_float(v.y << 16);
  a[3] += __uint_as_float(v.y & 0xffff0000u);
  a[4] += __uint_as_float(v.z << 16);
  a[5] += __uint_as_float(v.z & 0xffff0000u);
  a[6] += __uint_as_float(v.w << 16);
  a[7] += __uint_as_float(v.w & 0xffff0000u);
}

__device__ inline void acc4n(float* a, uint2 v) {
  a[0] += __uint_as_float(v.x << 16);
  a[1] += __uint_as_float(v.x & 0xffff0000u);
  a[2] += __uint_as_float(v.y << 16);
  a[3] += __uint_as_float(v.y & 0xffff0000u);
}

// ---------------- zero (deg + flags) ----------------

__global__ void k_zero(uint4* __restrict__ deg, int n16, uint4* __restrict__ flags) {
  int i = blockIdx.x * blockDim.x + threadIdx.x;
  if (i < n16) deg[i] = make_uint4(0, 0, 0, 0);
  if (i < 16) flags[i] = make_uint4(0, 0, 0, 0);
}

// ------ fused count + prep: blocks 0..63 do weight transpose/BN fold (hides under
// ------ the 800k-atomic degree count in blocks 64+) ------------------------------------

__global__ __launch_bounds__(256) void k_count_prep(
    const int* __restrict__ ei, int E, int* __restrict__ deg, int* __restrict__ posw,
    const float* __restrict__ W1, const float* __restrict__ W2,
    const float* __restrict__ W3,
    const float* __restrict__ g1, const float* __restrict__ be1,
    const float* __restrict__ m1, const float* __restrict__ v1,
    const float* __restrict__ g2, const float* __restrict__ be2,
    const float* __restrict__ m2, const float* __restrict__ v2,
    const float* __restrict__ b1, const float* __restrict__ b2,
    const float* __restrict__ b3,
    ushort* __restrict__ WT1, ushort* __restrict__ WT2, ushort* __restrict__ WT3,
    float* __restrict__ sc1, float* __restrict__ sh1,
    float* __restrict__ sc2, float* __restrict__ sh2,
    float* __restrict__ b3pad) {
  int b = blockIdx.x;
  int tid = threadIdx.x;
  if (b < 64) {                     // prep role: 64 blocks x 2 W-rows each
    int k = b * 2 + (tid >> 7);
    int n = tid & 127;
    WT1[n * 128 + k] = (ushort)f2bf(W1[k * 128 + n]);
    WT2[n * 128 + k] = (ushort)f2bf(W2[k * 128 + n]);
    WT3[n * 128 + k] = (n < 40) ? (ushort)f2bf(W3[k * 40 + n]) : (ushort)0;
    if (k == 0) {
      float s1 = g1[n] * rsqrtf(v1[n] + BN_EPS);
      sc1[n] = s1; sh1[n] = be1[n] + (b1[n] - m1[n]) * s1;    // bias folded in
      float s2 = g2[n] * rsqrtf(v2[n] + BN_EPS);
      sc2[n] = s2; sh2[n] = be2[n] + (b2[n] - m2[n]) * s2;
    } else if (k == 1 && n < 64) {
      b3pad[n] = (n < 40) ? b3[n] : 0.f;
    }
    return;
  }
  int e = (b - 64) * 256 + tid;     // count role
  if (e < E) posw[e] = atomicAdd(&deg[ei[E + e]], 1);
}

// single-pass scan with decoupled lookback (chunks <= 64, all blocks co-resident).
__global__ void k_scan(const int* __restrict__ deg, int* __restrict__ rowstart,
                       float* __restrict__ dis, int* __restrict__ flags,
                       int n, int E) {
  __shared__ int s[1024];
  __shared__ int spre;
  const int b = blockIdx.x;
  const int tid = threadIdx.x;
  int i = b * 1024 + tid;
  int v = (i < n) ? deg[i] : 0;
  if (i < n) dis[i] = rsqrtf((float)(v + 1));   // +1 self loop
  s[tid] = v;
  __syncthreads();
  for (int off = 1; off < 1024; off <<= 1) {
    int t = (tid >= off) ? s[tid - off] : 0;
    __syncthreads();
    s[tid] += t;
    __syncthreads();
  }
  if (tid == 0) {
    spre = 0;
    atomicExch(&flags[b], s[1023] + 1);         // publish own total
  }
  __syncthreads();
  if (tid < b) {                                 // wait for predecessors (<=48)
    int v2;
    do { v2 = atomicAdd(&flags[tid], 0); } while (v2 == 0);
    atomicAdd(&spre, v2 - 1);
  }
  __syncthreads();
  int pre = spre;
  if (i < n) rowstart[i] = pre + s[tid] - v;     // global exclusive prefix
  if (b == 0 && tid == 0) rowstart[n] = E;
}

// ---- MFMA GEMM: C[r][c] = dis[r] * (A[r][:] @ W[:][c]), bf16 out.  BM=64 tiles for
// ---- occupancy (782 blocks, ~3 waves/SIMD). 4 waves as 2x2 grid of 32x64 sub-tiles.
// ---- Optional fused CSR-fill role for blocks >= gemmBlocks (layer 1).

template <bool F32A, bool FILL>
__global__ __launch_bounds__(256) void k_gemm_bf16(const void* __restrict__ Ap,
                                                   const ushort* __restrict__ WT,
                                                   ushort* __restrict__ C,
                                                   const float* __restrict__ dis,
                                                   int nrows, int NC, int gemmBlocks,
                                                   const int* __restrict__ ei,
                                                   const int* __restrict__ rowstart,
                                                   const int* __restrict__ posw,
                                                   unsigned* __restrict__ slot, int E) {
  if (FILL && (int)blockIdx.x >= gemmBlocks) {
    int e = ((int)blockIdx.x - gemmBlocks) * 256 + threadIdx.x;
    if (e < E) slot[rowstart[ei[E + e]] + posw[e]] = (unsigned)ei[e];
    return;
  }
  __shared__ ushort As[64][80];
  __shared__ ushort Bs[128][80];
  const int tid  = threadIdx.x;
  const int lane = tid & 63;
  const int wid  = tid >> 6;
  const int wr   = wid >> 1, wc = wid & 1;   // 2x2: wave covers 32 rows x 64 cols
  const int row0 = blockIdx.x * 64;
  f32x4 acc[2][4] = {};

  const int mrow = lane & 15;
  const int kg   = (lane >> 4) * 8;

  for (int k0 = 0; k0 < 128; k0 += 64) {
    __syncthreads();
    for (int i = tid; i < 512; i += 256) {         // A tile: 64 rows x 64 bf16
      int r = i >> 3, c = (i & 7) * 8;
      uint4 w = make_uint4(0, 0, 0, 0);
      if (row0 + r < nrows) {
        if (F32A) {
          const float* A = (const float*)Ap;
          float4 v0 = *(const float4*)(A + (size_t)(row0 + r) * 128 + k0 + c);
          float4 v1 = *(const float4*)(A + (size_t)(row0 + r) * 128 + k0 + c + 4);
          w.x = f2bf(v0.x) | (f2bf(v0.y) << 16);
          w.y = f2bf(v0.z) | (f2bf(v0.w) << 16);
          w.z = f2bf(v1.x) | (f2bf(v1.y) << 16);
          w.w = f2bf(v1.z) | (f2bf(v1.w) << 16);
        } else {
          const ushort* A = (const ushort*)Ap;
          w = *(const uint4*)(A + (size_t)(row0 + r) * 128 + k0 + c);
        }
      }
      *(uint4*)(&As[r][c]) = w;
    }
    for (int i = tid; i < 1024; i += 256) {        // B tile: 128 n-rows x 64 bf16 (k)
      int r = i >> 3, c = (i & 7) * 8;
      *(uint4*)(&Bs[r][c]) = *(const uint4*)(WT + r * 128 + k0 + c);
    }
    __syncthreads();

#pragma unroll
    for (int ks = 0; ks < 2; ks++) {
      bf16x8 a[2], b[4];
#pragma unroll
      for (int f = 0; f < 2; f++)
        a[f] = *(const bf16x8*)(&As[wr * 32 + f * 16 + mrow][ks * 32 + kg]);
#pragma unroll
      for (int f = 0; f < 4; f++)
        b[f] = *(const bf16x8*)(&Bs[wc * 64 + f * 16 + mrow][ks * 32 + kg]);
#pragma unroll
      for (int fm = 0; fm < 2; fm++)
#pragma unroll
        for (int fn = 0; fn < 4; fn++)
          acc[fm][fn] = __builtin_amdgcn_mfma_f32_16x16x32_bf16(a[fm], b[fn], acc[fm][fn], 0, 0, 0);
    }
  }

  // C/D layout: col = lane&15, row = (lane>>4)*4 + reg
  const int rl = (lane >> 4) * 4;
  const int cl = lane & 15;
#pragma unroll
  for (int fm = 0; fm < 2; fm++) {
#pragma unroll
    for (int r = 0; r < 4; r++) {
      int row = row0 + wr * 32 + fm * 16 + rl + r;
      if (row >= nrows) continue;
      float dn = dis[row];
#pragma unroll
      for (int fn = 0; fn < 4; fn++) {
        int col = wc * 64 + fn * 16 + cl;
        if (col < NC) C[(size_t)row * NC + col] = (ushort)f2bf(acc[fm][fn][r] * dn);
      }
    }
  }
}

// ---- Aggregation (D=128): out = relu(sc*(dis[n]*(Σ h'[src] + h'[n])) + sh), bf16 ------
// r6-proven shape: wave = 4 edge-groups x 16 lanes; lane gathers 8 ch (16B); 4-deep ILP.

__global__ __launch_bounds__(256) void k_agg128b(const ushort* __restrict__ h,
                          const int* __restrict__ rowstart,
                          const unsigned* __restrict__ slot,
                          const float* __restrict__ dis,
                          const float* __restrict__ bnsc,
                          const float* __restrict__ bnsh,
                          ushort* __restrict__ out, int nnodes) {
  int node = blockIdx.x * 4 + threadIdx.y;
  if (node >= nnodes) return;
  int lane = threadIdx.x;
  int eg = lane >> 4, cl = lane & 15, c0 = cl * 8;
  int s = rowstart[node], e = rowstart[node + 1];
  int deg = e - s;
  unsigned mys = 0;
  if (lane < deg) mys = slot[s + lane];
  float a[8] = {0.f, 0.f, 0.f, 0.f, 0.f, 0.f, 0.f, 0.f};
  int nb = deg < 64 ? deg : 64;
  int i = eg;
  for (; i + 12 < nb; i += 16) {                 // 4 independent gathers in flight
    int s0 = __shfl((int)mys, i);
    int s1 = __shfl((int)mys, i + 4);
    int s2 = __shfl((int)mys, i + 8);
    int s3 = __shfl((int)mys, i + 12);
    uint4 h0 = *(const uint4*)(h + (size_t)s0 * 128 + c0);
    uint4 h1 = *(const uint4*)(h + (size_t)s1 * 128 + c0);
    uint4 h2 = *(const uint4*)(h + (size_t)s2 * 128 + c0);
    uint4 h3 = *(const uint4*)(h + (size_t)s3 * 128 + c0);
    acc8n(a, h0); acc8n(a, h1); acc8n(a, h2); acc8n(a, h3);
  }
  for (; i + 4 < nb; i += 8) {
    int s0 = __shfl((int)mys, i);
    int s1 = __shfl((int)mys, i + 4);
    uint4 h0 = *(const uint4*)(h + (size_t)s0 * 128 + c0);
    uint4 h1 = *(const uint4*)(h + (size_t)s1 * 128 + c0);
    acc8n(a, h0); acc8n(a, h1);
  }
  if (i < nb) {
    int s0 = __shfl((int)mys, i);
    uint4 h0 = *(const uint4*)(h + (size_t)s0 * 128 + c0);
    acc8n(a, h0);
  }
  for (int j = s + 64 + eg; j < e; j += 4) {     // rare tail (deg > 64)
    uint4 h0 = *(const uint4*)(h + (size_t)slot[j] * 128 + c0);
    acc8n(a, h0);
  }
#pragma unroll
  for (int j = 0; j < 8; j++) {
    a[j] += __shfl_xor(a[j], 16);
    a[j] += __shfl_xor(a[j], 32);
  }
  if (eg == 0) {
    uint4 hv = *(const uint4*)(h + (size_t)node * 128 + c0);
    acc8n(a, hv);                                 // self loop
    float dn = dis[node];
    float4 sc0 = *(const float4*)(bnsc + c0), sc1 = *(const float4*)(bnsc + c0 + 4);
    float4 sh0 = *(const float4*)(bnsh + c0), sh1 = *(const float4*)(bnsh + c0 + 4);
    float o0 = fmaxf(fmaf(a[0] * dn, sc0.x, sh0.x), 0.f);
    float o1 = fmaxf(fmaf(a[1] * dn, sc0.y, sh0.y), 0.f);
    float o2 = fmaxf(fmaf(a[2] * dn, sc0.z, sh0.z), 0.f);
    float o3 = fmaxf(fmaf(a[3] * dn, sc0.w, sh0.w), 0.f);
    float o4 = fmaxf(fmaf(a[4] * dn, sc1.x, sh1.x), 0.f);
    float o5 = fmaxf(fmaf(a[5] * dn, sc1.y, sh1.y), 0.f);
    float o6 = fmaxf(fmaf(a[6] * dn, sc1.z, sh1.z), 0.f);
    float o7 = fmaxf(fmaf(a[7] * dn, sc1.w, sh1.w), 0.f);
    uint4 w;
    w.x = f2bf(o0) | (f2bf(o1) << 16);
    w.y = f2bf(o2) | (f2bf(o3) << 16);
    w.z = f2bf(o4) | (f2bf(o5) << 16);
    w.w = f2bf(o6) | (f2bf(o7) << 16);
    *(uint4*)(out + (size_t)node * 128 + c0) = w;
  }
}

// -------- Aggregation (40-ch layer-3 rows) + log_softmax (fp32 out, 40 ch) -------------

__global__ __launch_bounds__(256) void k_agg40_lsm(const ushort* __restrict__ h,
                            const int* __restrict__ rowstart,
                            const unsigned* __restrict__ slot,
                            const float* __restrict__ dis,
                            const float* __restrict__ b3pad,
                            float* __restrict__ out, int nnodes) {
  int node = blockIdx.x * 4 + threadIdx.y;
  if (node >= nnodes) return;
  int lane = threadIdx.x;
  int eg = lane >> 4, cl = lane & 15, c0 = cl * 4;
  bool act = cl < 10;                            // channels 4*cl..4*cl+3 < 40
  int s = rowstart[node], e = rowstart[node + 1];
  int deg = e - s;
  unsigned mys = 0;
  if (lane < deg) mys = slot[s + lane];
  float a[4] = {0.f, 0.f, 0.f, 0.f};
  int nb = deg < 64 ? deg : 64;
  int i = eg;
  for (; i + 12 < nb; i += 16) {
    int s0 = __shfl((int)mys, i);
    int s1 = __shfl((int)mys, i + 4);
    int s2 = __shfl((int)mys, i + 8);
    int s3 = __shfl((int)mys, i + 12);
    if (act) {
      uint2 h0 = *(const uint2*)(h + (size_t)s0 * 40 + c0);
      uint2 h1 = *(const uint2*)(h + (size_t)s1 * 40 + c0);
      uint2 h2 = *(const uint2*)(h + (size_t)s2 * 40 + c0);
      uint2 h3 = *(const uint2*)(h + (size_t)s3 * 40 + c0);
      acc4n(a, h0); acc4n(a, h1); acc4n(a, h2); acc4n(a, h3);
    }
  }
  for (; i + 4 < nb; i += 8) {
    int s0 = __shfl((int)mys, i);
    int s1 = __shfl((int)mys, i + 4);
    if (act) {
      uint2 h0 = *(const uint2*)(h + (size_t)s0 * 40 + c0);
      uint2 h1 = *(const uint2*)(h + (size_t)s1 * 40 + c0);
      acc4n(a, h0); acc4n(a, h1);
    }
  }
  if (i < nb) {
    int s0 = __shfl((int)mys, i);
    if (act) acc4n(a, *(const uint2*)(h + (size_t)s0 * 40 + c0));
  }
  for (int j = s + 64 + eg; j < e; j += 4) {
    unsigned sj = slot[j];
    if (act) acc4n(a, *(const uint2*)(h + (size_t)sj * 40 + c0));
  }
#pragma unroll
  for (int j = 0; j < 4; j++) {
    a[j] += __shfl_xor(a[j], 16);
    a[j] += __shfl_xor(a[j], 32);
  }
  // self loop + dis scale + bias (identical across edge groups)
  if (act) {
    acc4n(a, *(const uint2*)(h + (size_t)node * 40 + c0));
    float dn = dis[node];
    float4 bb = *(const float4*)(b3pad + c0);
    a[0] = fmaf(a[0], dn, bb.x);
    a[1] = fmaf(a[1], dn, bb.y);
    a[2] = fmaf(a[2], dn, bb.z);
    a[3] = fmaf(a[3], dn, bb.w);
  }
  float m = act ? fmaxf(fmaxf(a[0], a[1]), fmaxf(a[2], a[3])) : -INFINITY;
#pragma unroll
  for (int off = 1; off < 16; off <<= 1) m = fmaxf(m, __shfl_xor(m, off));
  float ss = act ? (expf(a[0] - m) + expf(a[1] - m) + expf(a[2] - m) + expf(a[3] - m)) : 0.f;
#pragma unroll
  for (int off = 1; off < 16; off <<= 1) ss += __shfl_xor(ss, off);
  float lse = m + logf(ss);
  if (eg == 0 && act) {
    *(float4*)(out + (size_t)node * 40 + c0) =
        make_float4(a[0] - lse, a[1] - lse, a[2] - lse, a[3] - lse);
  }
}

// ---------------- launch ----------------

extern "C" void kernel_launch(void* const* d_in, const int* in_sizes, int n_in,
                              void* d_out, int out_size, void* d_ws, size_t ws_size,
                              hipStream_t stream) {
  const float* x   = (const float*)d_in[0];
  const int*   ei  = (const int*)d_in[1];
  const float* W1  = (const float*)d_in[2];
  const float* b1  = (const float*)d_in[3];
  const float* W2  = (const float*)d_in[4];
  const float* b2  = (const float*)d_in[5];
  const float* W3  = (const float*)d_in[6];
  const float* b3  = (const float*)d_in[7];
  const float* g1  = (const float*)d_in[8];
  const float* be1 = (const float*)d_in[9];
  const float* m1  = (const float*)d_in[10];
  const float* v1  = (const float*)d_in[11];
  const float* g2  = (const float*)d_in[12];
  const float* be2 = (const float*)d_in[13];
  const float* m2  = (const float*)d_in[14];
  const float* v2  = (const float*)d_in[15];

  const int N   = in_sizes[0] / 128;
  const int E   = in_sizes[1] / 2;

  float* outp = (float*)d_out;

  char* ws = (char*)d_ws;
  size_t off = 0;
  auto alloc = [&](size_t bytes) -> char* {
    char* p = ws + off;
    off = (off + bytes + 255) & ~(size_t)255;
    return p;
  };
  const int deg16 = (N + 3) / 4;
  int*      deg      = (int*)alloc((size_t)deg16 * 16);
  int*      flags    = (int*)alloc(64 * 4);
  int*      posw     = (int*)alloc((size_t)E * 4);
  int*      rowstart = (int*)alloc((size_t)(N + 1) * 4);
  float*    dis      = (float*)alloc((size_t)N * 4);
  unsigned* slot     = (unsigned*)alloc((size_t)E * 4);
  float*    sc1      = (float*)alloc(128 * 4);
  float*    sh1      = (float*)alloc(128 * 4);
  float*    sc2      = (float*)alloc(128 * 4);
  float*    sh2      = (float*)alloc(128 * 4);
  float*    b3pad    = (float*)alloc(64 * 4);
  ushort*   WT1      = (ushort*)alloc(128 * 128 * 2);
  ushort*   WT2      = (ushort*)alloc(128 * 128 * 2);
  ushort*   WT3      = (ushort*)alloc(128 * 128 * 2);
  ushort*   bufA     = (ushort*)alloc((size_t)N * 128 * 2);
  ushort*   bufB     = (ushort*)alloc((size_t)N * 128 * 2);
  ushort*   bufC     = (ushort*)alloc((size_t)N * 40 * 2);
  (void)ws_size;

  const int T = 256;
  const int chunks = (N + 1023) / 1024;   // 49 <= 64
  const int cBlocks = (E + 255) / 256;

  // zero -> fused count+prep -> single-pass scan
  k_zero<<<(deg16 + T - 1) / T, T, 0, stream>>>((uint4*)deg, deg16, (uint4*)flags);
  k_count_prep<<<64 + cBlocks, 256, 0, stream>>>(
      ei, E, deg, posw, W1, W2, W3, g1, be1, m1, v1, g2, be2, m2, v2,
      b1, b2, b3, WT1, WT2, WT3, sc1, sh1, sc2, sh2, b3pad);
  k_scan<<<chunks, 1024, 0, stream>>>(deg, rowstart, dis, flags, N, E);

  const int quads = (N + 3) / 4;
  dim3 aggBlk(64, 4);
  const int gBlocks = (N + 63) / 64;

  // Layer 1: GEMM (fp32 in, dis-scaled bf16 out) with CSR fill fused in extra blocks
  k_gemm_bf16<true, true><<<gBlocks + cBlocks, 256, 0, stream>>>(
      x, WT1, bufB, dis, N, 128, gBlocks, ei, rowstart, posw, slot, E);
  k_agg128b<<<quads, aggBlk, 0, stream>>>(bufB, rowstart, slot, dis, sc1, sh1, bufA, N);

  // Layer 2
  k_gemm_bf16<false, false><<<gBlocks, 256, 0, stream>>>(
      bufA, WT2, bufB, dis, N, 128, gBlocks, nullptr, nullptr, nullptr, nullptr, 0);
  k_agg128b<<<quads, aggBlk, 0, stream>>>(bufB, rowstart, slot, dis, sc2, sh2, bufA, N);

  // Layer 3 (40-ch rows) + log_softmax
  k_gemm_bf16<false, false><<<gBlocks, 256, 0, stream>>>(
      bufA, WT3, bufC, dis, N, 40, gBlocks, nullptr, nullptr, nullptr, nullptr, 0);
  k_agg40_lsm<<<quads, aggBlk, 0, stream>>>(bufC, rowstart, slot, dis, b3pad, outp, N);
}

// Round 11
// 170.449 us; speedup vs baseline: 1.7490x; 1.0820x over previous
//
#include <hip/hip_runtime.h>
#include <math.h>

#define BN_EPS 1e-5f

typedef __attribute__((ext_vector_type(8))) short bf16x8;
typedef __attribute__((ext_vector_type(4))) float f32x4;

__device__ inline unsigned f2bf(float f) {
  union { float f; unsigned u; } v; v.f = f;
  unsigned r = v.u + 0x7FFF + ((v.u >> 16) & 1);   // round-nearest-even
  return r >> 16;
}

__device__ inline void acc8n(float* a, uint4 v) {
  a[0] += __uint_as_float(v.x << 16);
  a[1] += __uint_as_float(v.x & 0xffff0000u);
  a[2] += __uint_as_float(v.y << 16);
  a[3] += __uint_as_float(v.y & 0xffff0000u);
  a[4] += __uint_as_float(v.z << 16);
  a[5] += __uint_as_float(v.z & 0xffff0000u);
  a[6] += __uint_as_float(v.w << 16);
  a[7] += __uint_as_float(v.w & 0xffff0000u);
}

__device__ inline void acc4n(float* a, uint2 v) {
  a[0] += __uint_as_float(v.x << 16);
  a[1] += __uint_as_float(v.x & 0xffff0000u);
  a[2] += __uint_as_float(v.y << 16);
  a[3] += __uint_as_float(v.y & 0xffff0000u);
}

// ---------------- zero (deg + flags) ----------------

__global__ void k_zero(uint4* __restrict__ deg, int n16, uint4* __restrict__ flags) {
  int i = blockIdx.x * blockDim.x + threadIdx.x;
  if (i < n16) deg[i] = make_uint4(0, 0, 0, 0);
  if (i < 16) flags[i] = make_uint4(0, 0, 0, 0);
}

// ------ fused count + prep: blocks 0..63 do weight transpose/BN fold (hides under
// ------ the 800k-atomic degree count in blocks 64+) ------------------------------------

__global__ __launch_bounds__(256) void k_count_prep(
    const int* __restrict__ ei, int E, int* __restrict__ deg, int* __restrict__ posw,
    const float* __restrict__ W1, const float* __restrict__ W2,
    const float* __restrict__ W3,
    const float* __restrict__ g1, const float* __restrict__ be1,
    const float* __restrict__ m1, const float* __restrict__ v1,
    const float* __restrict__ g2, const float* __restrict__ be2,
    const float* __restrict__ m2, const float* __restrict__ v2,
    const float* __restrict__ b1, const float* __restrict__ b2,
    const float* __restrict__ b3,
    ushort* __restrict__ WT1, ushort* __restrict__ WT2, ushort* __restrict__ WT3,
    float* __restrict__ sc1, float* __restrict__ sh1,
    float* __restrict__ sc2, float* __restrict__ sh2,
    float* __restrict__ b3pad) {
  int b = blockIdx.x;
  int tid = threadIdx.x;
  if (b < 64) {                     // prep role: 64 blocks x 2 W-rows each
    int k = b * 2 + (tid >> 7);
    int n = tid & 127;
    WT1[n * 128 + k] = (ushort)f2bf(W1[k * 128 + n]);
    WT2[n * 128 + k] = (ushort)f2bf(W2[k * 128 + n]);
    WT3[n * 128 + k] = (n < 40) ? (ushort)f2bf(W3[k * 40 + n]) : (ushort)0;
    if (k == 0) {
      float s1 = g1[n] * rsqrtf(v1[n] + BN_EPS);
      sc1[n] = s1; sh1[n] = be1[n] + (b1[n] - m1[n]) * s1;    // bias folded in
      float s2 = g2[n] * rsqrtf(v2[n] + BN_EPS);
      sc2[n] = s2; sh2[n] = be2[n] + (b2[n] - m2[n]) * s2;
    } else if (k == 1 && n < 64) {
      b3pad[n] = (n < 40) ? b3[n] : 0.f;
    }
    return;
  }
  int e = (b - 64) * 256 + tid;     // count role
  if (e < E) posw[e] = atomicAdd(&deg[ei[E + e]], 1);
}

// single-pass scan with decoupled lookback (chunks <= 64, all blocks co-resident).
__global__ void k_scan(const int* __restrict__ deg, int* __restrict__ rowstart,
                       float* __restrict__ dis, int* __restrict__ flags,
                       int n, int E) {
  __shared__ int s[1024];
  __shared__ int spre;
  const int b = blockIdx.x;
  const int tid = threadIdx.x;
  int i = b * 1024 + tid;
  int v = (i < n) ? deg[i] : 0;
  if (i < n) dis[i] = rsqrtf((float)(v + 1));   // +1 self loop
  s[tid] = v;
  __syncthreads();
  for (int off = 1; off < 1024; off <<= 1) {
    int t = (tid >= off) ? s[tid - off] : 0;
    __syncthreads();
    s[tid] += t;
    __syncthreads();
  }
  if (tid == 0) {
    spre = 0;
    atomicExch(&flags[b], s[1023] + 1);         // publish own total
  }
  __syncthreads();
  if (tid < b) {                                 // wait for predecessors (<=48)
    int v2;
    do { v2 = atomicAdd(&flags[tid], 0); } while (v2 == 0);
    atomicAdd(&spre, v2 - 1);
  }
  __syncthreads();
  int pre = spre;
  if (i < n) rowstart[i] = pre + s[tid] - v;     // global exclusive prefix
  if (b == 0 && tid == 0) rowstart[n] = E;
}

// ---- MFMA GEMM (NC=128): C[r][c] = dis[r] * (A[r][:] @ W[:][c]), bf16 out.  BM=64,
// ---- 4 waves as 2x2 grid of 32x64 sub-tiles. Optional fused CSR-fill role.

template <bool F32A, bool FILL>
__global__ __launch_bounds__(256) void k_gemm_bf16(const void* __restrict__ Ap,
                                                   const ushort* __restrict__ WT,
                                                   ushort* __restrict__ C,
                                                   const float* __restrict__ dis,
                                                   int nrows, int gemmBlocks,
                                                   const int* __restrict__ ei,
                                                   const int* __restrict__ rowstart,
                                                   const int* __restrict__ posw,
                                                   unsigned* __restrict__ slot, int E) {
  if (FILL && (int)blockIdx.x >= gemmBlocks) {
    int e = ((int)blockIdx.x - gemmBlocks) * 256 + threadIdx.x;
    if (e < E) slot[rowstart[ei[E + e]] + posw[e]] = (unsigned)ei[e];
    return;
  }
  __shared__ ushort As[64][80];
  __shared__ ushort Bs[128][80];
  const int tid  = threadIdx.x;
  const int lane = tid & 63;
  const int wid  = tid >> 6;
  const int wr   = wid >> 1, wc = wid & 1;   // 2x2: wave covers 32 rows x 64 cols
  const int row0 = blockIdx.x * 64;
  f32x4 acc[2][4] = {};

  const int mrow = lane & 15;
  const int kg   = (lane >> 4) * 8;

  for (int k0 = 0; k0 < 128; k0 += 64) {
    __syncthreads();
    for (int i = tid; i < 512; i += 256) {         // A tile: 64 rows x 64 bf16
      int r = i >> 3, c = (i & 7) * 8;
      uint4 w = make_uint4(0, 0, 0, 0);
      if (row0 + r < nrows) {
        if (F32A) {
          const float* A = (const float*)Ap;
          float4 v0 = *(const float4*)(A + (size_t)(row0 + r) * 128 + k0 + c);
          float4 v1 = *(const float4*)(A + (size_t)(row0 + r) * 128 + k0 + c + 4);
          w.x = f2bf(v0.x) | (f2bf(v0.y) << 16);
          w.y = f2bf(v0.z) | (f2bf(v0.w) << 16);
          w.z = f2bf(v1.x) | (f2bf(v1.y) << 16);
          w.w = f2bf(v1.z) | (f2bf(v1.w) << 16);
        } else {
          const ushort* A = (const ushort*)Ap;
          w = *(const uint4*)(A + (size_t)(row0 + r) * 128 + k0 + c);
        }
      }
      *(uint4*)(&As[r][c]) = w;
    }
    for (int i = tid; i < 1024; i += 256) {        // B tile: 128 n-rows x 64 bf16 (k)
      int r = i >> 3, c = (i & 7) * 8;
      *(uint4*)(&Bs[r][c]) = *(const uint4*)(WT + r * 128 + k0 + c);
    }
    __syncthreads();

#pragma unroll
    for (int ks = 0; ks < 2; ks++) {
      bf16x8 a[2], b[4];
#pragma unroll
      for (int f = 0; f < 2; f++)
        a[f] = *(const bf16x8*)(&As[wr * 32 + f * 16 + mrow][ks * 32 + kg]);
#pragma unroll
      for (int f = 0; f < 4; f++)
        b[f] = *(const bf16x8*)(&Bs[wc * 64 + f * 16 + mrow][ks * 32 + kg]);
#pragma unroll
      for (int fm = 0; fm < 2; fm++)
#pragma unroll
        for (int fn = 0; fn < 4; fn++)
          acc[fm][fn] = __builtin_amdgcn_mfma_f32_16x16x32_bf16(a[fm], b[fn], acc[fm][fn], 0, 0, 0);
    }
  }

  // C/D layout: col = lane&15, row = (lane>>4)*4 + reg
  const int rl = (lane >> 4) * 4;
  const int cl = lane & 15;
#pragma unroll
  for (int fm = 0; fm < 2; fm++) {
#pragma unroll
    for (int r = 0; r < 4; r++) {
      int row = row0 + wr * 32 + fm * 16 + rl + r;
      if (row >= nrows) continue;
      float dn = dis[row];
#pragma unroll
      for (int fn = 0; fn < 4; fn++) {
        int col = wc * 64 + fn * 16 + cl;
        C[(size_t)row * 128 + col] = (ushort)f2bf(acc[fm][fn][r] * dn);
      }
    }
  }
}

// ---- Narrow MFMA GEMM (NC=40, 40-ch rows out): BM=64, 4 waves = 4x16-row stripes,
// ---- 3 col-fragments (48 cols, cols 40..47 are zero-padded weights). 6 MFMA/wave.

__global__ __launch_bounds__(256) void k_gemm40(const ushort* __restrict__ A,
                                                const ushort* __restrict__ WT,
                                                ushort* __restrict__ C,
                                                const float* __restrict__ dis,
                                                int nrows) {
  __shared__ ushort As[64][80];
  __shared__ ushort Bs[48][80];
  const int tid  = threadIdx.x;
  const int lane = tid & 63;
  const int wid  = tid >> 6;
  const int row0 = blockIdx.x * 64;
  f32x4 acc[3] = {};

  const int mrow = lane & 15;
  const int kg   = (lane >> 4) * 8;

  for (int k0 = 0; k0 < 128; k0 += 64) {
    __syncthreads();
    for (int i = tid; i < 512; i += 256) {         // A tile: 64 rows x 64 bf16
      int r = i >> 3, c = (i & 7) * 8;
      uint4 w = make_uint4(0, 0, 0, 0);
      if (row0 + r < nrows) w = *(const uint4*)(A + (size_t)(row0 + r) * 128 + k0 + c);
      *(uint4*)(&As[r][c]) = w;
    }
    for (int i = tid; i < 384; i += 256) {         // B tile: 48 n-rows x 64 bf16 (k)
      int r = i >> 3, c = (i & 7) * 8;
      *(uint4*)(&Bs[r][c]) = *(const uint4*)(WT + r * 128 + k0 + c);
    }
    __syncthreads();

#pragma unroll
    for (int ks = 0; ks < 2; ks++) {
      bf16x8 a = *(const bf16x8*)(&As[wid * 16 + mrow][ks * 32 + kg]);
      bf16x8 b[3];
#pragma unroll
      for (int f = 0; f < 3; f++)
        b[f] = *(const bf16x8*)(&Bs[f * 16 + mrow][ks * 32 + kg]);
#pragma unroll
      for (int f = 0; f < 3; f++)
        acc[f] = __builtin_amdgcn_mfma_f32_16x16x32_bf16(a, b[f], acc[f], 0, 0, 0);
    }
  }

  const int rl = (lane >> 4) * 4;
  const int cl = lane & 15;
#pragma unroll
  for (int r = 0; r < 4; r++) {
    int row = row0 + wid * 16 + rl + r;
    if (row >= nrows) continue;
    float dn = dis[row];
#pragma unroll
    for (int f = 0; f < 3; f++) {
      int col = f * 16 + cl;
      if (col < 40) C[(size_t)row * 40 + col] = (ushort)f2bf(acc[f][r] * dn);
    }
  }
}

// ---- Aggregation (D=128): out = relu(sc*(dis[n]*(Σ h'[src] + h'[n])) + sh), bf16 ------
// r6-proven shape: wave = 4 edge-groups x 16 lanes; lane gathers 8 ch (16B); 4-deep ILP.

__global__ __launch_bounds__(256) void k_agg128b(const ushort* __restrict__ h,
                          const int* __restrict__ rowstart,
                          const unsigned* __restrict__ slot,
                          const float* __restrict__ dis,
                          const float* __restrict__ bnsc,
                          const float* __restrict__ bnsh,
                          ushort* __restrict__ out, int nnodes) {
  int node = blockIdx.x * 4 + threadIdx.y;
  if (node >= nnodes) return;
  int lane = threadIdx.x;
  int eg = lane >> 4, cl = lane & 15, c0 = cl * 8;
  int s = rowstart[node], e = rowstart[node + 1];
  int deg = e - s;
  unsigned mys = 0;
  if (lane < deg) mys = slot[s + lane];
  float a[8] = {0.f, 0.f, 0.f, 0.f, 0.f, 0.f, 0.f, 0.f};
  int nb = deg < 64 ? deg : 64;
  int i = eg;
  for (; i + 12 < nb; i += 16) {                 // 4 independent gathers in flight
    int s0 = __shfl((int)mys, i);
    int s1 = __shfl((int)mys, i + 4);
    int s2 = __shfl((int)mys, i + 8);
    int s3 = __shfl((int)mys, i + 12);
    uint4 h0 = *(const uint4*)(h + (size_t)s0 * 128 + c0);
    uint4 h1 = *(const uint4*)(h + (size_t)s1 * 128 + c0);
    uint4 h2 = *(const uint4*)(h + (size_t)s2 * 128 + c0);
    uint4 h3 = *(const uint4*)(h + (size_t)s3 * 128 + c0);
    acc8n(a, h0); acc8n(a, h1); acc8n(a, h2); acc8n(a, h3);
  }
  for (; i + 4 < nb; i += 8) {
    int s0 = __shfl((int)mys, i);
    int s1 = __shfl((int)mys, i + 4);
    uint4 h0 = *(const uint4*)(h + (size_t)s0 * 128 + c0);
    uint4 h1 = *(const uint4*)(h + (size_t)s1 * 128 + c0);
    acc8n(a, h0); acc8n(a, h1);
  }
  if (i < nb) {
    int s0 = __shfl((int)mys, i);
    uint4 h0 = *(const uint4*)(h + (size_t)s0 * 128 + c0);
    acc8n(a, h0);
  }
  for (int j = s + 64 + eg; j < e; j += 4) {     // rare tail (deg > 64)
    uint4 h0 = *(const uint4*)(h + (size_t)slot[j] * 128 + c0);
    acc8n(a, h0);
  }
#pragma unroll
  for (int j = 0; j < 8; j++) {
    a[j] += __shfl_xor(a[j], 16);
    a[j] += __shfl_xor(a[j], 32);
  }
  if (eg == 0) {
    uint4 hv = *(const uint4*)(h + (size_t)node * 128 + c0);
    acc8n(a, hv);                                 // self loop
    float dn = dis[node];
    float4 sc0 = *(const float4*)(bnsc + c0), sc1 = *(const float4*)(bnsc + c0 + 4);
    float4 sh0 = *(const float4*)(bnsh + c0), sh1 = *(const float4*)(bnsh + c0 + 4);
    float o0 = fmaxf(fmaf(a[0] * dn, sc0.x, sh0.x), 0.f);
    float o1 = fmaxf(fmaf(a[1] * dn, sc0.y, sh0.y), 0.f);
    float o2 = fmaxf(fmaf(a[2] * dn, sc0.z, sh0.z), 0.f);
    float o3 = fmaxf(fmaf(a[3] * dn, sc0.w, sh0.w), 0.f);
    float o4 = fmaxf(fmaf(a[4] * dn, sc1.x, sh1.x), 0.f);
    float o5 = fmaxf(fmaf(a[5] * dn, sc1.y, sh1.y), 0.f);
    float o6 = fmaxf(fmaf(a[6] * dn, sc1.z, sh1.z), 0.f);
    float o7 = fmaxf(fmaf(a[7] * dn, sc1.w, sh1.w), 0.f);
    uint4 w;
    w.x = f2bf(o0) | (f2bf(o1) << 16);
    w.y = f2bf(o2) | (f2bf(o3) << 16);
    w.z = f2bf(o4) | (f2bf(o5) << 16);
    w.w = f2bf(o6) | (f2bf(o7) << 16);
    *(uint4*)(out + (size_t)node * 128 + c0) = w;
  }
}

// -------- Aggregation (40-ch rows) + log_softmax: 2 nodes per wave -----------------
// Half-wave (32 lanes) per node: 2 edge-groups x 16 lanes; lane loads 4 ch (8B).

__global__ __launch_bounds__(256) void k_agg40_lsm(const ushort* __restrict__ h,
                            const int* __restrict__ rowstart,
                            const unsigned* __restrict__ slot,
                            const float* __restrict__ dis,
                            const float* __restrict__ b3pad,
                            float* __restrict__ out, int nnodes) {
  int lane = threadIdx.x;
  int node = blockIdx.x * 8 + threadIdx.y * 2 + (lane >> 5);
  if (node >= nnodes) return;
  int eg = (lane >> 4) & 1, cl = lane & 15, c0 = cl * 4;
  bool act = cl < 10;                            // channels 4*cl..4*cl+3 < 40
  int s = rowstart[node], e = rowstart[node + 1];
  int deg = e - s;
  int l32 = lane & 31;
  unsigned mys = 0;
  if (l32 < deg) mys = slot[s + l32];
  float a[4] = {0.f, 0.f, 0.f, 0.f};
  int nb = deg < 32 ? deg : 32;
  int i = eg;
  for (; i + 6 < nb; i += 8) {                   // 4 gathers in flight per half-wave
    int s0 = __shfl((int)mys, i, 32);
    int s1 = __shfl((int)mys, i + 2, 32);
    int s2 = __shfl((int)mys, i + 4, 32);
    int s3 = __shfl((int)mys, i + 6, 32);
    if (act) {
      uint2 h0 = *(const uint2*)(h + (size_t)s0 * 40 + c0);
      uint2 h1 = *(const uint2*)(h + (size_t)s1 * 40 + c0);
      uint2 h2 = *(const uint2*)(h + (size_t)s2 * 40 + c0);
      uint2 h3 = *(const uint2*)(h + (size_t)s3 * 40 + c0);
      acc4n(a, h0); acc4n(a, h1); acc4n(a, h2); acc4n(a, h3);
    }
  }
  for (; i < nb; i += 2) {
    int s0 = __shfl((int)mys, i, 32);
    if (act) acc4n(a, *(const uint2*)(h + (size_t)s0 * 40 + c0));
  }
  for (int j = s + 32 + eg; j < e; j += 2) {     // rare tail (deg > 32)
    unsigned sj = slot[j];
    if (act) acc4n(a, *(const uint2*)(h + (size_t)sj * 40 + c0));
  }
#pragma unroll
  for (int j = 0; j < 4; j++) a[j] += __shfl_xor(a[j], 16);   // merge 2 edge groups
  // self loop + dis scale + bias (identical across edge groups)
  if (act) {
    acc4n(a, *(const uint2*)(h + (size_t)node * 40 + c0));
    float dn = dis[node];
    float4 bb = *(const float4*)(b3pad + c0);
    a[0] = fmaf(a[0], dn, bb.x);
    a[1] = fmaf(a[1], dn, bb.y);
    a[2] = fmaf(a[2], dn, bb.z);
    a[3] = fmaf(a[3], dn, bb.w);
  }
  float m = act ? fmaxf(fmaxf(a[0], a[1]), fmaxf(a[2], a[3])) : -INFINITY;
#pragma unroll
  for (int off = 1; off < 16; off <<= 1) m = fmaxf(m, __shfl_xor(m, off));
  float ss = act ? (expf(a[0] - m) + expf(a[1] - m) + expf(a[2] - m) + expf(a[3] - m)) : 0.f;
#pragma unroll
  for (int off = 1; off < 16; off <<= 1) ss += __shfl_xor(ss, off);
  float lse = m + logf(ss);
  if (eg == 0 && act) {
    *(float4*)(out + (size_t)node * 40 + c0) =
        make_float4(a[0] - lse, a[1] - lse, a[2] - lse, a[3] - lse);
  }
}

// ---------------- launch ----------------

extern "C" void kernel_launch(void* const* d_in, const int* in_sizes, int n_in,
                              void* d_out, int out_size, void* d_ws, size_t ws_size,
                              hipStream_t stream) {
  const float* x   = (const float*)d_in[0];
  const int*   ei  = (const int*)d_in[1];
  const float* W1  = (const float*)d_in[2];
  const float* b1  = (const float*)d_in[3];
  const float* W2  = (const float*)d_in[4];
  const float* b2  = (const float*)d_in[5];
  const float* W3  = (const float*)d_in[6];
  const float* b3  = (const float*)d_in[7];
  const float* g1  = (const float*)d_in[8];
  const float* be1 = (const float*)d_in[9];
  const float* m1  = (const float*)d_in[10];
  const float* v1  = (const float*)d_in[11];
  const float* g2  = (const float*)d_in[12];
  const float* be2 = (const float*)d_in[13];
  const float* m2  = (const float*)d_in[14];
  const float* v2  = (const float*)d_in[15];

  const int N   = in_sizes[0] / 128;
  const int E   = in_sizes[1] / 2;

  float* outp = (float*)d_out;

  char* ws = (char*)d_ws;
  size_t off = 0;
  auto alloc = [&](size_t bytes) -> char* {
    char* p = ws + off;
    off = (off + bytes + 255) & ~(size_t)255;
    return p;
  };
  const int deg16 = (N + 3) / 4;
  int*      deg      = (int*)alloc((size_t)deg16 * 16);
  int*      flags    = (int*)alloc(64 * 4);
  int*      posw     = (int*)alloc((size_t)E * 4);
  int*      rowstart = (int*)alloc((size_t)(N + 1) * 4);
  float*    dis      = (float*)alloc((size_t)N * 4);
  unsigned* slot     = (unsigned*)alloc((size_t)E * 4);
  float*    sc1      = (float*)alloc(128 * 4);
  float*    sh1      = (float*)alloc(128 * 4);
  float*    sc2      = (float*)alloc(128 * 4);
  float*    sh2      = (float*)alloc(128 * 4);
  float*    b3pad    = (float*)alloc(64 * 4);
  ushort*   WT1      = (ushort*)alloc(128 * 128 * 2);
  ushort*   WT2      = (ushort*)alloc(128 * 128 * 2);
  ushort*   WT3      = (ushort*)alloc(128 * 128 * 2);
  ushort*   bufA     = (ushort*)alloc((size_t)N * 128 * 2);
  ushort*   bufB     = (ushort*)alloc((size_t)N * 128 * 2);
  ushort*   bufC     = (ushort*)alloc((size_t)N * 40 * 2);
  (void)ws_size;

  const int T = 256;
  const int chunks = (N + 1023) / 1024;   // 49 <= 64
  const int cBlocks = (E + 255) / 256;

  // zero -> fused count+prep -> single-pass scan
  k_zero<<<(deg16 + T - 1) / T, T, 0, stream>>>((uint4*)deg, deg16, (uint4*)flags);
  k_count_prep<<<64 + cBlocks, 256, 0, stream>>>(
      ei, E, deg, posw, W1, W2, W3, g1, be1, m1, v1, g2, be2, m2, v2,
      b1, b2, b3, WT1, WT2, WT3, sc1, sh1, sc2, sh2, b3pad);
  k_scan<<<chunks, 1024, 0, stream>>>(deg, rowstart, dis, flags, N, E);

  const int quads = (N + 3) / 4;
  dim3 aggBlk(64, 4);
  const int gBlocks = (N + 63) / 64;

  // Layer 1: GEMM (fp32 in, dis-scaled bf16 out) with CSR fill fused in extra blocks
  k_gemm_bf16<true, true><<<gBlocks + cBlocks, 256, 0, stream>>>(
      x, WT1, bufB, dis, N, gBlocks, ei, rowstart, posw, slot, E);
  k_agg128b<<<quads, aggBlk, 0, stream>>>(bufB, rowstart, slot, dis, sc1, sh1, bufA, N);

  // Layer 2
  k_gemm_bf16<false, false><<<gBlocks, 256, 0, stream>>>(
      bufA, WT2, bufB, dis, N, gBlocks, nullptr, nullptr, nullptr, nullptr, 0);
  k_agg128b<<<quads, aggBlk, 0, stream>>>(bufB, rowstart, slot, dis, sc2, sh2, bufA, N);

  // Layer 3 (narrow GEMM, 40-ch rows) + log_softmax (2 nodes/wave)
  k_gemm40<<<gBlocks, 256, 0, stream>>>(bufA, WT3, bufC, dis, N);
  k_agg40_lsm<<<(N + 7) / 8, aggBlk, 0, stream>>>(bufC, rowstart, slot, dis, b3pad, outp, N);
}

// Round 12
// 168.259 us; speedup vs baseline: 1.7717x; 1.0130x over previous
//
#include <hip/hip_runtime.h>
#include <math.h>

#define BN_EPS 1e-5f

typedef __attribute__((ext_vector_type(8))) short bf16x8;
typedef __attribute__((ext_vector_type(4))) float f32x4;

__device__ inline unsigned f2bf(float f) {
  union { float f; unsigned u; } v; v.f = f;
  unsigned r = v.u + 0x7FFF + ((v.u >> 16) & 1);   // round-nearest-even
  return r >> 16;
}

__device__ inline void acc8n(float* a, uint4 v) {
  a[0] += __uint_as_float(v.x << 16);
  a[1] += __uint_as_float(v.x & 0xffff0000u);
  a[2] += __uint_as_float(v.y << 16);
  a[3] += __uint_as_float(v.y & 0xffff0000u);
  a[4] += __uint_as_float(v.z << 16);
  a[5] += __uint_as_float(v.z & 0xffff0000u);
  a[6] += __uint_as_float(v.w << 16);
  a[7] += __uint_as_float(v.w & 0xffff0000u);
}

__device__ inline void acc4n(float* a, uint2 v) {
  a[0] += __uint_as_float(v.x << 16);
  a[1] += __uint_as_float(v.x & 0xffff0000u);
  a[2] += __uint_as_float(v.y << 16);
  a[3] += __uint_as_float(v.y & 0xffff0000u);
}

// ---------------- zero (deg + flags) ----------------

__global__ void k_zero(uint4* __restrict__ deg, int n16, uint4* __restrict__ flags) {
  int i = blockIdx.x * blockDim.x + threadIdx.x;
  if (i < n16) deg[i] = make_uint4(0, 0, 0, 0);
  if (i < 16) flags[i] = make_uint4(0, 0, 0, 0);
}

// ------ fused count + prep: blocks 0..63 do weight transpose/BN fold (hides under
// ------ the 800k-atomic degree count in blocks 64+) ------------------------------------

__global__ __launch_bounds__(256) void k_count_prep(
    const int* __restrict__ ei, int E, int* __restrict__ deg, int* __restrict__ posw,
    const float* __restrict__ W1, const float* __restrict__ W2,
    const float* __restrict__ W3,
    const float* __restrict__ g1, const float* __restrict__ be1,
    const float* __restrict__ m1, const float* __restrict__ v1,
    const float* __restrict__ g2, const float* __restrict__ be2,
    const float* __restrict__ m2, const float* __restrict__ v2,
    const float* __restrict__ b1, const float* __restrict__ b2,
    const float* __restrict__ b3,
    ushort* __restrict__ WT1, ushort* __restrict__ WT2, ushort* __restrict__ WT3,
    float* __restrict__ sc1, float* __restrict__ sh1,
    float* __restrict__ sc2, float* __restrict__ sh2,
    float* __restrict__ b3pad) {
  int b = blockIdx.x;
  int tid = threadIdx.x;
  if (b < 64) {                     // prep role: 64 blocks x 2 W-rows each
    int k = b * 2 + (tid >> 7);
    int n = tid & 127;
    WT1[n * 128 + k] = (ushort)f2bf(W1[k * 128 + n]);
    WT2[n * 128 + k] = (ushort)f2bf(W2[k * 128 + n]);
    WT3[n * 128 + k] = (n < 40) ? (ushort)f2bf(W3[k * 40 + n]) : (ushort)0;
    if (k == 0) {
      float s1 = g1[n] * rsqrtf(v1[n] + BN_EPS);
      sc1[n] = s1; sh1[n] = be1[n] + (b1[n] - m1[n]) * s1;    // bias folded in
      float s2 = g2[n] * rsqrtf(v2[n] + BN_EPS);
      sc2[n] = s2; sh2[n] = be2[n] + (b2[n] - m2[n]) * s2;
    } else if (k == 1 && n < 64) {
      b3pad[n] = (n < 40) ? b3[n] : 0.f;
    }
    return;
  }
  int e = (b - 64) * 256 + tid;     // count role
  if (e < E) posw[e] = atomicAdd(&deg[ei[E + e]], 1);
}

// single-pass scan with decoupled lookback (chunks <= 64, all blocks co-resident).
__global__ void k_scan(const int* __restrict__ deg, int* __restrict__ rowstart,
                       float* __restrict__ dis, int* __restrict__ flags,
                       int n, int E) {
  __shared__ int s[1024];
  __shared__ int spre;
  const int b = blockIdx.x;
  const int tid = threadIdx.x;
  int i = b * 1024 + tid;
  int v = (i < n) ? deg[i] : 0;
  if (i < n) dis[i] = rsqrtf((float)(v + 1));   // +1 self loop
  s[tid] = v;
  __syncthreads();
  for (int off = 1; off < 1024; off <<= 1) {
    int t = (tid >= off) ? s[tid - off] : 0;
    __syncthreads();
    s[tid] += t;
    __syncthreads();
  }
  if (tid == 0) {
    spre = 0;
    atomicExch(&flags[b], s[1023] + 1);         // publish own total
  }
  __syncthreads();
  if (tid < b) {                                 // wait for predecessors (<=48)
    int v2;
    do { v2 = atomicAdd(&flags[tid], 0); } while (v2 == 0);
    atomicAdd(&spre, v2 - 1);
  }
  __syncthreads();
  int pre = spre;
  if (i < n) rowstart[i] = pre + s[tid] - v;     // global exclusive prefix
  if (b == 0 && tid == 0) rowstart[n] = E;
}

// ---- MFMA GEMM (NC=128): C[r][c] = dis[r] * (A[r][:] @ W[:][c]), bf16 out.  BM=64,
// ---- 4 waves as 2x2 grid of 32x64 sub-tiles. Optional fused CSR-fill role.

template <bool F32A, bool FILL>
__global__ __launch_bounds__(256) void k_gemm_bf16(const void* __restrict__ Ap,
                                                   const ushort* __restrict__ WT,
                                                   ushort* __restrict__ C,
                                                   const float* __restrict__ dis,
                                                   int nrows, int gemmBlocks,
                                                   const int* __restrict__ ei,
                                                   const int* __restrict__ rowstart,
                                                   const int* __restrict__ posw,
                                                   unsigned* __restrict__ slot, int E) {
  if (FILL && (int)blockIdx.x >= gemmBlocks) {
    int e = ((int)blockIdx.x - gemmBlocks) * 256 + threadIdx.x;
    if (e < E) slot[rowstart[ei[E + e]] + posw[e]] = (unsigned)ei[e];
    return;
  }
  __shared__ ushort As[64][80];
  __shared__ ushort Bs[128][80];
  const int tid  = threadIdx.x;
  const int lane = tid & 63;
  const int wid  = tid >> 6;
  const int wr   = wid >> 1, wc = wid & 1;   // 2x2: wave covers 32 rows x 64 cols
  const int row0 = blockIdx.x * 64;
  f32x4 acc[2][4] = {};

  const int mrow = lane & 15;
  const int kg   = (lane >> 4) * 8;

  for (int k0 = 0; k0 < 128; k0 += 64) {
    __syncthreads();
    for (int i = tid; i < 512; i += 256) {         // A tile: 64 rows x 64 bf16
      int r = i >> 3, c = (i & 7) * 8;
      uint4 w = make_uint4(0, 0, 0, 0);
      if (row0 + r < nrows) {
        if (F32A) {
          const float* A = (const float*)Ap;
          float4 v0 = *(const float4*)(A + (size_t)(row0 + r) * 128 + k0 + c);
          float4 v1 = *(const float4*)(A + (size_t)(row0 + r) * 128 + k0 + c + 4);
          w.x = f2bf(v0.x) | (f2bf(v0.y) << 16);
          w.y = f2bf(v0.z) | (f2bf(v0.w) << 16);
          w.z = f2bf(v1.x) | (f2bf(v1.y) << 16);
          w.w = f2bf(v1.z) | (f2bf(v1.w) << 16);
        } else {
          const ushort* A = (const ushort*)Ap;
          w = *(const uint4*)(A + (size_t)(row0 + r) * 128 + k0 + c);
        }
      }
      *(uint4*)(&As[r][c]) = w;
    }
    for (int i = tid; i < 1024; i += 256) {        // B tile: 128 n-rows x 64 bf16 (k)
      int r = i >> 3, c = (i & 7) * 8;
      *(uint4*)(&Bs[r][c]) = *(const uint4*)(WT + r * 128 + k0 + c);
    }
    __syncthreads();

#pragma unroll
    for (int ks = 0; ks < 2; ks++) {
      bf16x8 a[2], b[4];
#pragma unroll
      for (int f = 0; f < 2; f++)
        a[f] = *(const bf16x8*)(&As[wr * 32 + f * 16 + mrow][ks * 32 + kg]);
#pragma unroll
      for (int f = 0; f < 4; f++)
        b[f] = *(const bf16x8*)(&Bs[wc * 64 + f * 16 + mrow][ks * 32 + kg]);
#pragma unroll
      for (int fm = 0; fm < 2; fm++)
#pragma unroll
        for (int fn = 0; fn < 4; fn++)
          acc[fm][fn] = __builtin_amdgcn_mfma_f32_16x16x32_bf16(a[fm], b[fn], acc[fm][fn], 0, 0, 0);
    }
  }

  // C/D layout: col = lane&15, row = (lane>>4)*4 + reg
  const int rl = (lane >> 4) * 4;
  const int cl = lane & 15;
#pragma unroll
  for (int fm = 0; fm < 2; fm++) {
#pragma unroll
    for (int r = 0; r < 4; r++) {
      int row = row0 + wr * 32 + fm * 16 + rl + r;
      if (row >= nrows) continue;
      float dn = dis[row];
#pragma unroll
      for (int fn = 0; fn < 4; fn++) {
        int col = wc * 64 + fn * 16 + cl;
        C[(size_t)row * 128 + col] = (ushort)f2bf(acc[fm][fn][r] * dn);
      }
    }
  }
}

// ---- Narrow MFMA GEMM (NC=40, 40-ch rows out): BM=64, 4 waves = 4x16-row stripes,
// ---- 3 col-fragments (48 cols, cols 40..47 are zero-padded weights). 6 MFMA/wave.

__global__ __launch_bounds__(256) void k_gemm40(const ushort* __restrict__ A,
                                                const ushort* __restrict__ WT,
                                                ushort* __restrict__ C,
                                                const float* __restrict__ dis,
                                                int nrows) {
  __shared__ ushort As[64][80];
  __shared__ ushort Bs[48][80];
  const int tid  = threadIdx.x;
  const int lane = tid & 63;
  const int wid  = tid >> 6;
  const int row0 = blockIdx.x * 64;
  f32x4 acc[3] = {};

  const int mrow = lane & 15;
  const int kg   = (lane >> 4) * 8;

  for (int k0 = 0; k0 < 128; k0 += 64) {
    __syncthreads();
    for (int i = tid; i < 512; i += 256) {         // A tile: 64 rows x 64 bf16
      int r = i >> 3, c = (i & 7) * 8;
      uint4 w = make_uint4(0, 0, 0, 0);
      if (row0 + r < nrows) w = *(const uint4*)(A + (size_t)(row0 + r) * 128 + k0 + c);
      *(uint4*)(&As[r][c]) = w;
    }
    for (int i = tid; i < 384; i += 256) {         // B tile: 48 n-rows x 64 bf16 (k)
      int r = i >> 3, c = (i & 7) * 8;
      *(uint4*)(&Bs[r][c]) = *(const uint4*)(WT + r * 128 + k0 + c);
    }
    __syncthreads();

#pragma unroll
    for (int ks = 0; ks < 2; ks++) {
      bf16x8 a = *(const bf16x8*)(&As[wid * 16 + mrow][ks * 32 + kg]);
      bf16x8 b[3];
#pragma unroll
      for (int f = 0; f < 3; f++)
        b[f] = *(const bf16x8*)(&Bs[f * 16 + mrow][ks * 32 + kg]);
#pragma unroll
      for (int f = 0; f < 3; f++)
        acc[f] = __builtin_amdgcn_mfma_f32_16x16x32_bf16(a, b[f], acc[f], 0, 0, 0);
    }
  }

  const int rl = (lane >> 4) * 4;
  const int cl = lane & 15;
#pragma unroll
  for (int r = 0; r < 4; r++) {
    int row = row0 + wid * 16 + rl + r;
    if (row >= nrows) continue;
    float dn = dis[row];
#pragma unroll
    for (int f = 0; f < 3; f++) {
      int col = f * 16 + cl;
      if (col < 40) C[(size_t)row * 40 + col] = (ushort)f2bf(acc[f][r] * dn);
    }
  }
}

// ---- Aggregation (D=128): out = relu(sc*(dis[n]*(Σ h'[src] + h'[n])) + sh), bf16 ------
// 2 nodes per wave: half-wave = 2 edge-groups x 16 lanes; lane gathers 8 ch (16B).
// 4-deep unroll -> 8 gathers in flight per wave (2x the old MLP).

__global__ __launch_bounds__(256) void k_agg128b(const ushort* __restrict__ h,
                          const int* __restrict__ rowstart,
                          const unsigned* __restrict__ slot,
                          const float* __restrict__ dis,
                          const float* __restrict__ bnsc,
                          const float* __restrict__ bnsh,
                          ushort* __restrict__ out, int nnodes) {
  int lane = threadIdx.x;
  int node = blockIdx.x * 8 + threadIdx.y * 2 + (lane >> 5);
  if (node >= nnodes) return;
  int l32 = lane & 31;
  int eg = l32 >> 4;                 // edge group within half-wave (0..1)
  int cl = lane & 15, c0 = cl * 8;
  int s = rowstart[node], e = rowstart[node + 1];
  int deg = e - s;
  unsigned mys = 0;
  if (l32 < deg) mys = slot[s + l32];             // covers deg <= 32
  float a[8] = {0.f, 0.f, 0.f, 0.f, 0.f, 0.f, 0.f, 0.f};
  int nb = deg < 32 ? deg : 32;
  int i = eg;
  for (; i + 6 < nb; i += 8) {                    // 4 gathers in flight per half-wave
    int s0 = __shfl((int)mys, i, 32);
    int s1 = __shfl((int)mys, i + 2, 32);
    int s2 = __shfl((int)mys, i + 4, 32);
    int s3 = __shfl((int)mys, i + 6, 32);
    uint4 h0 = *(const uint4*)(h + (size_t)s0 * 128 + c0);
    uint4 h1 = *(const uint4*)(h + (size_t)s1 * 128 + c0);
    uint4 h2 = *(const uint4*)(h + (size_t)s2 * 128 + c0);
    uint4 h3 = *(const uint4*)(h + (size_t)s3 * 128 + c0);
    acc8n(a, h0); acc8n(a, h1); acc8n(a, h2); acc8n(a, h3);
  }
  for (; i < nb; i += 2) {
    int s0 = __shfl((int)mys, i, 32);
    uint4 h0 = *(const uint4*)(h + (size_t)s0 * 128 + c0);
    acc8n(a, h0);
  }
  for (int j = s + 32 + eg; j < e; j += 2) {      // rare tail (deg > 32)
    uint4 h0 = *(const uint4*)(h + (size_t)slot[j] * 128 + c0);
    acc8n(a, h0);
  }
#pragma unroll
  for (int j = 0; j < 8; j++) a[j] += __shfl_xor(a[j], 16);   // merge 2 edge groups
  if (eg == 0) {                                  // 16 lanes per node write the row
    uint4 hv = *(const uint4*)(h + (size_t)node * 128 + c0);
    acc8n(a, hv);                                 // self loop
    float dn = dis[node];
    float4 sc0 = *(const float4*)(bnsc + c0), sc1 = *(const float4*)(bnsc + c0 + 4);
    float4 sh0 = *(const float4*)(bnsh + c0), sh1 = *(const float4*)(bnsh + c0 + 4);
    float o0 = fmaxf(fmaf(a[0] * dn, sc0.x, sh0.x), 0.f);
    float o1 = fmaxf(fmaf(a[1] * dn, sc0.y, sh0.y), 0.f);
    float o2 = fmaxf(fmaf(a[2] * dn, sc0.z, sh0.z), 0.f);
    float o3 = fmaxf(fmaf(a[3] * dn, sc0.w, sh0.w), 0.f);
    float o4 = fmaxf(fmaf(a[4] * dn, sc1.x, sh1.x), 0.f);
    float o5 = fmaxf(fmaf(a[5] * dn, sc1.y, sh1.y), 0.f);
    float o6 = fmaxf(fmaf(a[6] * dn, sc1.z, sh1.z), 0.f);
    float o7 = fmaxf(fmaf(a[7] * dn, sc1.w, sh1.w), 0.f);
    uint4 w;
    w.x = f2bf(o0) | (f2bf(o1) << 16);
    w.y = f2bf(o2) | (f2bf(o3) << 16);
    w.z = f2bf(o4) | (f2bf(o5) << 16);
    w.w = f2bf(o6) | (f2bf(o7) << 16);
    *(uint4*)(out + (size_t)node * 128 + c0) = w;
  }
}

// -------- Aggregation (40-ch rows) + log_softmax: 2 nodes per wave -----------------
// Half-wave (32 lanes) per node: 2 edge-groups x 16 lanes; lane loads 4 ch (8B).

__global__ __launch_bounds__(256) void k_agg40_lsm(const ushort* __restrict__ h,
                            const int* __restrict__ rowstart,
                            const unsigned* __restrict__ slot,
                            const float* __restrict__ dis,
                            const float* __restrict__ b3pad,
                            float* __restrict__ out, int nnodes) {
  int lane = threadIdx.x;
  int node = blockIdx.x * 8 + threadIdx.y * 2 + (lane >> 5);
  if (node >= nnodes) return;
  int eg = (lane >> 4) & 1, cl = lane & 15, c0 = cl * 4;
  bool act = cl < 10;                            // channels 4*cl..4*cl+3 < 40
  int s = rowstart[node], e = rowstart[node + 1];
  int deg = e - s;
  int l32 = lane & 31;
  unsigned mys = 0;
  if (l32 < deg) mys = slot[s + l32];
  float a[4] = {0.f, 0.f, 0.f, 0.f};
  int nb = deg < 32 ? deg : 32;
  int i = eg;
  for (; i + 6 < nb; i += 8) {                   // 4 gathers in flight per half-wave
    int s0 = __shfl((int)mys, i, 32);
    int s1 = __shfl((int)mys, i + 2, 32);
    int s2 = __shfl((int)mys, i + 4, 32);
    int s3 = __shfl((int)mys, i + 6, 32);
    if (act) {
      uint2 h0 = *(const uint2*)(h + (size_t)s0 * 40 + c0);
      uint2 h1 = *(const uint2*)(h + (size_t)s1 * 40 + c0);
      uint2 h2 = *(const uint2*)(h + (size_t)s2 * 40 + c0);
      uint2 h3 = *(const uint2*)(h + (size_t)s3 * 40 + c0);
      acc4n(a, h0); acc4n(a, h1); acc4n(a, h2); acc4n(a, h3);
    }
  }
  for (; i < nb; i += 2) {
    int s0 = __shfl((int)mys, i, 32);
    if (act) acc4n(a, *(const uint2*)(h + (size_t)s0 * 40 + c0));
  }
  for (int j = s + 32 + eg; j < e; j += 2) {     // rare tail (deg > 32)
    unsigned sj = slot[j];
    if (act) acc4n(a, *(const uint2*)(h + (size_t)sj * 40 + c0));
  }
#pragma unroll
  for (int j = 0; j < 4; j++) a[j] += __shfl_xor(a[j], 16);   // merge 2 edge groups
  // self loop + dis scale + bias (identical across edge groups)
  if (act) {
    acc4n(a, *(const uint2*)(h + (size_t)node * 40 + c0));
    float dn = dis[node];
    float4 bb = *(const float4*)(b3pad + c0);
    a[0] = fmaf(a[0], dn, bb.x);
    a[1] = fmaf(a[1], dn, bb.y);
    a[2] = fmaf(a[2], dn, bb.z);
    a[3] = fmaf(a[3], dn, bb.w);
  }
  float m = act ? fmaxf(fmaxf(a[0], a[1]), fmaxf(a[2], a[3])) : -INFINITY;
#pragma unroll
  for (int off = 1; off < 16; off <<= 1) m = fmaxf(m, __shfl_xor(m, off));
  float ss = act ? (expf(a[0] - m) + expf(a[1] - m) + expf(a[2] - m) + expf(a[3] - m)) : 0.f;
#pragma unroll
  for (int off = 1; off < 16; off <<= 1) ss += __shfl_xor(ss, off);
  float lse = m + logf(ss);
  if (eg == 0 && act) {
    *(float4*)(out + (size_t)node * 40 + c0) =
        make_float4(a[0] - lse, a[1] - lse, a[2] - lse, a[3] - lse);
  }
}

// ---------------- launch ----------------

extern "C" void kernel_launch(void* const* d_in, const int* in_sizes, int n_in,
                              void* d_out, int out_size, void* d_ws, size_t ws_size,
                              hipStream_t stream) {
  const float* x   = (const float*)d_in[0];
  const int*   ei  = (const int*)d_in[1];
  const float* W1  = (const float*)d_in[2];
  const float* b1  = (const float*)d_in[3];
  const float* W2  = (const float*)d_in[4];
  const float* b2  = (const float*)d_in[5];
  const float* W3  = (const float*)d_in[6];
  const float* b3  = (const float*)d_in[7];
  const float* g1  = (const float*)d_in[8];
  const float* be1 = (const float*)d_in[9];
  const float* m1  = (const float*)d_in[10];
  const float* v1  = (const float*)d_in[11];
  const float* g2  = (const float*)d_in[12];
  const float* be2 = (const float*)d_in[13];
  const float* m2  = (const float*)d_in[14];
  const float* v2  = (const float*)d_in[15];

  const int N   = in_sizes[0] / 128;
  const int E   = in_sizes[1] / 2;

  float* outp = (float*)d_out;

  char* ws = (char*)d_ws;
  size_t off = 0;
  auto alloc = [&](size_t bytes) -> char* {
    char* p = ws + off;
    off = (off + bytes + 255) & ~(size_t)255;
    return p;
  };
  const int deg16 = (N + 3) / 4;
  int*      deg      = (int*)alloc((size_t)deg16 * 16);
  int*      flags    = (int*)alloc(64 * 4);
  int*      posw     = (int*)alloc((size_t)E * 4);
  int*      rowstart = (int*)alloc((size_t)(N + 1) * 4);
  float*    dis      = (float*)alloc((size_t)N * 4);
  unsigned* slot     = (unsigned*)alloc((size_t)E * 4);
  float*    sc1      = (float*)alloc(128 * 4);
  float*    sh1      = (float*)alloc(128 * 4);
  float*    sc2      = (float*)alloc(128 * 4);
  float*    sh2      = (float*)alloc(128 * 4);
  float*    b3pad    = (float*)alloc(64 * 4);
  ushort*   WT1      = (ushort*)alloc(128 * 128 * 2);
  ushort*   WT2      = (ushort*)alloc(128 * 128 * 2);
  ushort*   WT3      = (ushort*)alloc(128 * 128 * 2);
  ushort*   bufA     = (ushort*)alloc((size_t)N * 128 * 2);
  ushort*   bufB     = (ushort*)alloc((size_t)N * 128 * 2);
  ushort*   bufC     = (ushort*)alloc((size_t)N * 40 * 2);
  (void)ws_size;

  const int T = 256;
  const int chunks = (N + 1023) / 1024;   // 49 <= 64
  const int cBlocks = (E + 255) / 256;

  // zero -> fused count+prep -> single-pass scan
  k_zero<<<(deg16 + T - 1) / T, T, 0, stream>>>((uint4*)deg, deg16, (uint4*)flags);
  k_count_prep<<<64 + cBlocks, 256, 0, stream>>>(
      ei, E, deg, posw, W1, W2, W3, g1, be1, m1, v1, g2, be2, m2, v2,
      b1, b2, b3, WT1, WT2, WT3, sc1, sh1, sc2, sh2, b3pad);
  k_scan<<<chunks, 1024, 0, stream>>>(deg, rowstart, dis, flags, N, E);

  dim3 aggBlk(64, 4);
  const int aggGrid = (N + 7) / 8;        // 2 nodes per wave, 8 per block
  const int gBlocks = (N + 63) / 64;

  // Layer 1: GEMM (fp32 in, dis-scaled bf16 out) with CSR fill fused in extra blocks
  k_gemm_bf16<true, true><<<gBlocks + cBlocks, 256, 0, stream>>>(
      x, WT1, bufB, dis, N, gBlocks, ei, rowstart, posw, slot, E);
  k_agg128b<<<aggGrid, aggBlk, 0, stream>>>(bufB, rowstart, slot, dis, sc1, sh1, bufA, N);

  // Layer 2
  k_gemm_bf16<false, false><<<gBlocks, 256, 0, stream>>>(
      bufA, WT2, bufB, dis, N, gBlocks, nullptr, nullptr, nullptr, nullptr, 0);
  k_agg128b<<<aggGrid, aggBlk, 0, stream>>>(bufB, rowstart, slot, dis, sc2, sh2, bufA, N);

  // Layer 3 (narrow GEMM, 40-ch rows) + log_softmax (2 nodes/wave)
  k_gemm40<<<gBlocks, 256, 0, stream>>>(bufA, WT3, bufC, dis, N);
  k_agg40_lsm<<<aggGrid, aggBlk, 0, stream>>>(bufC, rowstart, slot, dis, b3pad, outp, N);
}